// Round 8
// baseline (653.281 us; speedup 1.0000x reference)
//
#include <hip/hip_runtime.h>
#include <hip/hip_bf16.h>
#include <hip/hip_fp16.h>
#include <math.h>

#define HD    128
#define EIN   325
#define PST   136      // edge tile row stride (f16), 16B-aligned
#define DST   72       // dis feature row stride (f16): 144B rows, 16B-aligned
#define NST   264      // node A-tile row stride (f16)
#define XST   136      // node x1 tile row stride
#define IST   408      // init A-tile row stride (400+8)

typedef _Float16 half8 __attribute__((ext_vector_type(8)));
typedef _Float16 half4 __attribute__((ext_vector_type(4)));
typedef _Float16 half2v __attribute__((ext_vector_type(2)));
typedef float    floatx16 __attribute__((ext_vector_type(16)));

// intra-wave LDS RAW fence (cross-lane write->read). Also a compiler memory fence.
#define WSYNC() __asm__ volatile("s_waitcnt lgkmcnt(0)" ::: "memory")

// fast silu: v_exp + v_rcp (approx) instead of IEEE div sequence
__device__ __forceinline__ float silu_f(float x) {
    return x * __builtin_amdgcn_rcpf(1.0f + __expf(-x));
}

// ---- generic weight prep: fp32 [m][Ktot][Nn] rows [krow0, krow0+Kact) -> fp16 [m][Nn][Kpad]
__global__ void k_wprep(const float* __restrict__ src, _Float16* __restrict__ dst,
                        int Ktot, int krow0, int Kact, int Nn, int Kpad, int nmat) {
    int idx = blockIdx.x * 256 + threadIdx.x;
    int per = Nn * Kpad;
    if (idx >= nmat * per) return;
    int m = idx / per, r = idx - m * per;
    int n = r / Kpad, k = r - n * Kpad;
    float v = (k < Kact) ? src[(size_t)m * Ktot * Nn + (size_t)(krow0 + k) * Nn + n] : 0.f;
    dst[idx] = (_Float16)v;
}

// ---- tiny kernels ----
__global__ void k_latip(const float* __restrict__ lat, float* __restrict__ latip, int G) {
    int idx = blockIdx.x * 256 + threadIdx.x;
    if (idx >= G * 9) return;
    int g = idx / 9, ij = idx - g * 9, i = ij / 3, k = ij - (ij / 3) * 3;
    const float* L = lat + g * 9;
    latip[idx] = L[i*3+0]*L[k*3+0] + L[i*3+1]*L[k*3+1] + L[i*3+2]*L[k*3+2];
}

__global__ void k_hist(const int* __restrict__ ei1, int* __restrict__ cnt, int E) {
    int idx = blockIdx.x * 256 + threadIdx.x;
    if (idx < E) atomicAdd(&cnt[ei1[idx]], 1);
}

__global__ void k_deginv(const int* __restrict__ cnt, float* __restrict__ deginv, int N) {
    int idx = blockIdx.x * 256 + threadIdx.x;
    if (idx < N) deginv[idx] = 1.0f / fmaxf((float)cnt[idx], 1.0f);
}

__global__ __launch_bounds__(1024) void k_scan(const int* __restrict__ cnt,
                                               int* __restrict__ head, int N) {
    __shared__ int part[1024];
    int tid = threadIdx.x;
    int chunk = (N + 1023) >> 10;
    int start = tid * chunk, stop = min(start + chunk, N);
    int s = 0;
    for (int i = start; i < stop; ++i) s += cnt[i];
    part[tid] = s;
    __syncthreads();
    for (int off = 1; off < 1024; off <<= 1) {
        int v = (tid >= off) ? part[tid - off] : 0;
        __syncthreads();
        part[tid] += v;
        __syncthreads();
    }
    int run = (tid > 0) ? part[tid - 1] : 0;
    for (int i = start; i < stop; ++i) { head[i] = run; run += cnt[i]; }
}

__global__ void k_scatter(const int* __restrict__ ei1, int* __restrict__ head,
                          int* __restrict__ perm, int E) {
    int e = blockIdx.x * 256 + threadIdx.x;
    if (e < E) {
        int d = ei1[e];
        int pos = atomicAdd(&head[d], 1);
        perm[pos] = e;
    }
}

// ---- sorted edge meta (dis features computed in-kernel in k_edge) ----
__global__ void k_esort(const int* __restrict__ ei, const int* __restrict__ n2g,
                        const float* __restrict__ fc, const int* __restrict__ perm,
                        int* __restrict__ eaS, int* __restrict__ ebS, int* __restrict__ egS,
                        float* __restrict__ fdS, int E) {
    int s = blockIdx.x * 256 + threadIdx.x;
    if (s >= E) return;
    int e = perm[s];
    int a = ei[e], b = ei[E + e];
    eaS[s] = a; ebS[s] = b; egS[s] = n2g[a];
    #pragma unroll
    for (int d = 0; d < 3; ++d) {
        float sh = fc[b * 3 + d] - fc[a * 3 + d];
        fdS[s * 3 + d] = sh - floorf(sh + 0.5f + 1e-4f);
    }
}

// ---- per-graph table: R[l][g][c] = latip[g] @ W1lat[l] + eb1[l] ----
__global__ void k_rlat(const float* __restrict__ latip, const float* __restrict__ ew1,
                       const float* __restrict__ eb1, _Float16* __restrict__ R16, int G) {
    int idx = blockIdx.x * 256 + threadIdx.x;
    if (idx >= 4 * G * HD) return;
    int l = idx / (G * HD), r = idx - l * (G * HD), g = r >> 7, c = r & 127;
    const float* W  = ew1 + (size_t)l * EIN * HD + 256 * HD;  // k-rows 256..264
    const float* lp = latip + g * 9;
    float s = eb1[l * HD + c];
    #pragma unroll
    for (int j = 0; j < 9; ++j) s = fmaf(lp[j], W[j * HD + c], s);
    R16[idx] = (_Float16)s;
}

__global__ void k_fin(const float* __restrict__ outsum, const float* __restrict__ deginv,
                      float* __restrict__ out, int N) {
    int idx = blockIdx.x * 256 + threadIdx.x;
    if (idx < N * 3) out[idx] = outsum[idx] * deginv[idx / 3];
}

// ---- node init fused with first P/Q ----
__global__ __launch_bounds__(256) void k_init_pq(
    const int* __restrict__ at, const float* __restrict__ t,
    const float* __restrict__ embed, const _Float16* __restrict__ latwT,
    const float* __restrict__ lat_b, float* __restrict__ h,
    _Float16* __restrict__ h16,
    const _Float16* __restrict__ WaT, const _Float16* __restrict__ WbT,
    _Float16* __restrict__ P16, _Float16* __restrict__ Q16, int N)
{
    __shared__ __align__(16) _Float16 xs[64 * IST];   // 51 KB
    __shared__ int   atL[64];
    __shared__ float tL[64];
    __shared__ float frL[128];
    int tid = threadIdx.x;
    int n0  = blockIdx.x * 64;

    if (tid < 64) {
        int node = n0 + tid;
        atL[tid] = (node < N) ? at[node] - 1 : 0;
        tL[tid]  = (node < N) ? t[node] : 0.f;
    }
    if (tid < 128) frL[tid] = __expf(-(float)tid * 0.07252236514f);
    __syncthreads();

    for (int c = tid; c < 64 * 32; c += 256) {       // embed cols 0..127
        int row = c >> 5, p = c & 31;
        float4 v = {0, 0, 0, 0};
        if (n0 + row < N) v = *(const float4*)(embed + (size_t)atL[row] * HD + p * 4);
        _Float16* d = xs + row * IST + p * 4;
        d[0] = (_Float16)v.x; d[1] = (_Float16)v.y; d[2] = (_Float16)v.z; d[3] = (_Float16)v.w;
    }
    for (int c = tid; c < 64 * 272; c += 256) {      // sin/cos cols 128..383 + pad
        int row = c / 272, j = c - row * 272;
        float v = 0.f;
        if (j < 256 && n0 + row < N) {
            int k = j & 127;
            float a = tL[row] * frL[k];
            v = (j < 128) ? __sinf(a) : __cosf(a);
        }
        xs[row * IST + 128 + j] = (_Float16)v;
    }
    __syncthreads();

    int lane = tid & 63, wv = tid >> 6;
    int l31 = lane & 31, lh = lane >> 5;
    int rm = (wv >> 1) * 32, cb = (wv & 1) * 64;
    int n0c = cb + 2 * l31, n1c = n0c + 1;           // interleaved col ownership

    floatx16 acc0 = {}, acc1 = {};
    {
        const _Float16* ap  = xs + (size_t)(rm + l31) * IST + lh * 8;
        const _Float16* bp0 = latwT + (size_t)n0c * 400 + lh * 8;
        const _Float16* bp1 = latwT + (size_t)n1c * 400 + lh * 8;
        for (int ks = 0; ks < 25; ++ks) {
            half8 a  = *(const half8*)(ap  + ks * 16);
            acc0 = __builtin_amdgcn_mfma_f32_32x32x16_f16(a, *(const half8*)(bp0 + ks * 16), acc0, 0, 0, 0);
            acc1 = __builtin_amdgcn_mfma_f32_32x32x16_f16(a, *(const half8*)(bp1 + ks * 16), acc1, 0, 0, 0);
        }
    }
    __syncthreads();   // all waves done reading xs A-tile

    {
        float2 bb = *(const float2*)(lat_b + n0c);
        #pragma unroll
        for (int r = 0; r < 16; ++r) {
            int row = rm + (r & 3) + 8 * (r >> 2) + 4 * lh;
            int node = n0 + row;
            float v0 = acc0[r] + bb.x, v1 = acc1[r] + bb.y;
            half2v h2; h2[0] = (_Float16)v0; h2[1] = (_Float16)v1;
            if (node < N) {
                *(float2*)(h + (size_t)node * HD + n0c) = make_float2(v0, v1);
                *(half2v*)(h16 + (size_t)node * HD + n0c) = h2;
            }
            *(half2v*)(xs + row * PST + n0c) = h2;   // stage for PQ GEMMs
        }
    }
    __syncthreads();

    // P/Q GEMMs: wave wv&1 selects matrix; cols 4*l31+i (adjacent quad per lane)
    {
        const _Float16* BT  = (wv & 1) ? WbT : WaT;
        _Float16*       OUT = (wv & 1) ? Q16 : P16;
        floatx16 acc[4] = {};
        const _Float16* ap = xs + (size_t)(rm + l31) * PST + lh * 8;
        for (int ks = 0; ks < 8; ++ks) {
            half8 a = *(const half8*)(ap + ks * 16);
            #pragma unroll
            for (int i = 0; i < 4; ++i) {
                half8 b = *(const half8*)(BT + (size_t)(4 * l31 + i) * HD + ks * 16 + lh * 8);
                acc[i] = __builtin_amdgcn_mfma_f32_32x32x16_f16(a, b, acc[i], 0, 0, 0);
            }
        }
        #pragma unroll
        for (int r = 0; r < 16; ++r) {
            int row = rm + (r & 3) + 8 * (r >> 2) + 4 * lh;
            int node = n0 + row;
            if (node < N) {
                half4 o;
                #pragma unroll
                for (int i = 0; i < 4; ++i) o[i] = (_Float16)acc[i][r];
                *(half4*)(OUT + (size_t)node * HD + 4 * l31) = o;
            }
        }
    }
}

// ---- fused edge kernel: 128-thread blocks, 2 waves share one 32-edge tile ----
// Column split: wave w owns cols [w*64, w*64+64). LDS ~9.6 KB/block -> up to
// 16 blocks/CU (32 waves). Pair barriers couple only 2 phase-aligned waves.
// dis features built redundantly by both waves into the tile (overlay), read
// back as MFMA A-fragments, then overwritten by PQR staging.
template <bool LAST>
__global__ __launch_bounds__(128, 5) void k_edge(
    const int* __restrict__ eaS, const int* __restrict__ ebS,
    const int* __restrict__ egS, const float* __restrict__ fdS,
    const _Float16* __restrict__ P16, const _Float16* __restrict__ Q16,
    const _Float16* __restrict__ R16, const _Float16* __restrict__ WdT,
    const _Float16* __restrict__ W2T, const float* __restrict__ b2,
    const _Float16* __restrict__ cw1T, const float* __restrict__ cb1,
    const float* __restrict__ cw2,
    float* __restrict__ aggsum, float* __restrict__ outsum, int E)
{
    __shared__ __align__(16) _Float16 xt[32 * PST];     // 8.7 KB shared tile
    __shared__ int   eaW[32], ebW[32], egW[32];          // 384 B
    __shared__ float fdW[LAST ? 32 : 1][3];
    __shared__ float gateW[LAST ? 32 : 1];

    int tid  = threadIdx.x;
    int wv   = tid >> 6, lane = tid & 63;
    int l31  = lane & 31, lh = lane >> 5;
    int s0   = blockIdx.x * 32;
    int base = wv * 64;                                  // owned col-half
    int c0   = base + 2 * l31, c1 = c0 + 1;              // owned col pair

    // ---- P0: meta + dis build (redundant in both waves; same values -> benign)
    if (lane < 32) {
        int s = s0 + lane;
        int a = 0, b = -1, g = 0;
        if (s < E) { a = eaS[s]; b = ebS[s]; g = egS[s]; }
        eaW[lane] = a; ebW[lane] = b; egW[lane] = g;
        if (LAST) {
            float f0 = 0.f, f1 = 0.f, f2 = 0.f;
            if (s < E) { f0 = fdS[s*3]; f1 = fdS[s*3+1]; f2 = fdS[s*3+2]; }
            fdW[lane][0] = f0; fdW[lane][1] = f1; fdW[lane][2] = f2;
            gateW[lane] = 0.f;
        }
    }
    // dis features -> xt as [32][DST]; lane (l31,lh): edge s0+l31, lh=0 sin / lh=1 cos
    {
        int s = s0 + l31;
        float fd3[3] = {0.f, 0.f, 0.f};
        if (s < E) { fd3[0] = fdS[s*3]; fd3[1] = fdS[s*3+1]; fd3[2] = fdS[s*3+2]; }
        _Float16* dr = xt + l31 * DST + lh * 30;
        #pragma unroll
        for (int d = 0; d < 3; ++d) {
            float ang = 6.283185307179586f * fd3[d];
            float s1 = __sinf(ang), ca = __cosf(ang);
            float tc = 2.f * ca;
            float m2 = lh ? 1.f : 0.f;       // w=0: cos=1, sin=0
            float m1 = lh ? ca  : s1;        // w=1
            half2v h01; h01[0] = (_Float16)m2; h01[1] = (_Float16)m1;
            *(half2v*)(dr + 10 * d) = h01;
            #pragma unroll
            for (int w = 2; w < 10; w += 2) {
                float a0 = tc * m1 - m2;
                float a1 = tc * a0 - m1;
                half2v hh; hh[0] = (_Float16)a0; hh[1] = (_Float16)a1;
                *(half2v*)(dr + 10 * d + w) = hh;
                m2 = a0; m1 = a1;
            }
        }
        half2v z; z[0] = (_Float16)0.f; z[1] = (_Float16)0.f;
        *(half2v*)(xt + l31 * DST + 60) = z;
        *(half2v*)(xt + l31 * DST + 62) = z;
    }
    WSYNC();                                             // own writes visible

    // ---- af[4] from LDS in A-fragment order (k = 16ks + 8lh + j)
    half8 af[4];
    {
        const _Float16* dp = xt + l31 * DST + lh * 8;
        af[0] = *(const half8*)(dp);      af[1] = *(const half8*)(dp + 16);
        af[2] = *(const half8*)(dp + 32); af[3] = *(const half8*)(dp + 48);
    }
    __syncthreads();                                     // B1: both waves done with dis

    // ---- PQR gather + stage own col-half (32 rows x 64 cols)
    #pragma unroll
    for (int k = 0; k < 4; ++k) {
        int idx = lane + 64 * k;                         // 0..255
        int row = idx >> 3;
        int p8  = base + (idx & 7) * 8;
        int a = eaW[row];
        int b = ebW[row]; if (b < 0) b = 0;
        int g = egW[row];
        half8 pv = *(const half8*)(P16 + (size_t)a * HD + p8);
        half8 qv = *(const half8*)(Q16 + (size_t)b * HD + p8);
        half8 rv = *(const half8*)(R16 + (size_t)g * HD + p8);
        *(half8*)(xt + row * PST + p8) = pv + qv + rv;
    }

    // ---- dis GEMM: K = 64, A from regs, 2 col-blocks (cols c0, c1)
    floatx16 acc0 = {}, acc1 = {};
    {
        const _Float16* bb0 = WdT + (size_t)c0 * 64 + lh * 8;
        #pragma unroll
        for (int ks = 0; ks < 4; ++ks) {
            acc0 = __builtin_amdgcn_mfma_f32_32x32x16_f16(af[ks], *(const half8*)(bb0 + ks * 16), acc0, 0, 0, 0);
            acc1 = __builtin_amdgcn_mfma_f32_32x32x16_f16(af[ks], *(const half8*)(bb0 + 64 + ks * 16), acc1, 0, 0, 0);
        }
    }
    WSYNC();                                             // own staging writes drained

    // ---- x1 = silu(accD + PQR), lane-owned half2 (cols c0,c1 in own half)
    #pragma unroll
    for (int r = 0; r < 16; ++r) {
        int row = (r & 3) + 8 * (r >> 2) + 4 * lh;
        half2v pq = *(const half2v*)(xt + row * PST + c0);
        half2v o;
        o[0] = (_Float16)silu_f(acc0[r] + (float)pq[0]);
        o[1] = (_Float16)silu_f(acc1[r] + (float)pq[1]);
        *(half2v*)(xt + row * PST + c0) = o;
    }
    __syncthreads();                                     // B2: full x1 tile visible

    // ---- GEMM2: ef = silu(x1 @ W2 + b2), K = 128 (A reads full rows)
    acc0 = (floatx16){}; acc1 = (floatx16){};
    {
        const _Float16* bb0 = W2T + (size_t)c0 * HD + lh * 8;
        for (int ks = 0; ks < 8; ++ks) {
            half8 a = *(const half8*)(xt + (size_t)l31 * PST + ks * 16 + lh * 8);
            acc0 = __builtin_amdgcn_mfma_f32_32x32x16_f16(a, *(const half8*)(bb0 + ks * 16), acc0, 0, 0, 0);
            acc1 = __builtin_amdgcn_mfma_f32_32x32x16_f16(a, *(const half8*)(bb0 + HD + ks * 16), acc1, 0, 0, 0);
        }
    }
    __syncthreads();                                     // B3: A-reads done before overwrite

    // ---- ef -> xt (own cells)
    {
        float2 b2v = *(const float2*)(b2 + c0);
        #pragma unroll
        for (int r = 0; r < 16; ++r) {
            int row = (r & 3) + 8 * (r >> 2) + 4 * lh;
            half2v o;
            o[0] = (_Float16)silu_f(acc0[r] + b2v.x);
            o[1] = (_Float16)silu_f(acc1[r] + b2v.y);
            *(half2v*)(xt + row * PST + c0) = o;
        }
    }

    if (!LAST) {
        WSYNC();                                         // own-wave ef visible (own half only)
        // ---- run-reduced scatter: wave scatters its own col-half.
        // lane: col pair c2 = base + 2*l31, rows lh*16 .. lh*16+15 (boundary
        // dest split between lh halves costs one extra atomic - correct).
        int c2 = base + 2 * l31;
        int r0 = lh * 16;
        float sx = 0.f, sy = 0.f;
        int cur = -1;
        for (int r = r0; r < r0 + 16; ++r) {
            int d = ebW[r];
            half2v v = *(const half2v*)(xt + r * PST + c2);
            float vx = (float)v[0], vy = (float)v[1];
            if (d != cur) {
                if (cur >= 0) {
                    atomicAdd(&aggsum[(size_t)cur * HD + c2],     sx);
                    atomicAdd(&aggsum[(size_t)cur * HD + c2 + 1], sy);
                }
                cur = d; sx = vx; sy = vy;
            } else { sx += vx; sy += vy; }
        }
        if (cur >= 0) {
            atomicAdd(&aggsum[(size_t)cur * HD + c2],     sx);
            atomicAdd(&aggsum[(size_t)cur * HD + c2 + 1], sy);
        }
    } else {
        __syncthreads();                                 // B4: full ef tile visible
        // ---- GEMM3: g1 = silu(ef @ cw1 + cb1); gate = g1 @ cw2
        acc0 = (floatx16){}; acc1 = (floatx16){};
        {
            const _Float16* bb0 = cw1T + (size_t)c0 * HD + lh * 8;
            for (int ks = 0; ks < 8; ++ks) {
                half8 a = *(const half8*)(xt + (size_t)l31 * PST + ks * 16 + lh * 8);
                acc0 = __builtin_amdgcn_mfma_f32_32x32x16_f16(a, *(const half8*)(bb0 + ks * 16), acc0, 0, 0, 0);
                acc1 = __builtin_amdgcn_mfma_f32_32x32x16_f16(a, *(const half8*)(bb0 + HD + ks * 16), acc1, 0, 0, 0);
            }
        }
        float2 cbv = *(const float2*)(cb1 + c0);
        float2 wv2 = *(const float2*)(cw2 + c0);
        #pragma unroll
        for (int r = 0; r < 16; ++r) {
            float p = silu_f(acc0[r] + cbv.x) * wv2.x + silu_f(acc1[r] + cbv.y) * wv2.y;
            p += __shfl_xor(p, 16);
            p += __shfl_xor(p, 8);
            p += __shfl_xor(p, 4);
            p += __shfl_xor(p, 2);
            p += __shfl_xor(p, 1);
            if (l31 == 0) {
                int row = (r & 3) + 8 * (r >> 2) + 4 * lh;
                atomicAdd(&gateW[row], p);               // both waves contribute 64-col partials
            }
        }
        __syncthreads();                                 // B5: gates complete
        if (wv == 0 && lane < 32) {
            int r = lane, d = ebW[r];
            if (d >= 0 && (r == 0 || ebW[r - 1] != d)) {
                float sx = 0.f, sy = 0.f, sz = 0.f;
                for (int q = r; q < 32 && ebW[q] == d; ++q) {
                    float g = gateW[q];
                    sx += fdW[q][0] * g;
                    sy += fdW[q][1] * g;
                    sz += fdW[q][2] * g;
                }
                atomicAdd(&outsum[d * 3 + 0], sx);
                atomicAdd(&outsum[d * 3 + 1], sy);
                atomicAdd(&outsum[d * 3 + 2], sz);
            }
        }
    }
}

// ---- fused node update + next-layer P/Q: 32-row tiles, waves split over columns ----
__global__ __launch_bounds__(256) void k_node_pq(
    float* __restrict__ h, _Float16* __restrict__ h16,
    float* __restrict__ aggsum, const float* __restrict__ deginv,
    const _Float16* __restrict__ W1T, const float* __restrict__ b1,
    const _Float16* __restrict__ W2T, const float* __restrict__ b2,
    const _Float16* __restrict__ WaT, const _Float16* __restrict__ WbT,
    _Float16* __restrict__ P16, _Float16* __restrict__ Q16, int N)
{
    __shared__ __align__(16) _Float16 xs[32 * NST];   // 16.9 KB
    _Float16* x1s = xs;

    int tid = threadIdx.x;
    int n0  = blockIdx.x * 32;

    for (int c = tid; c < 32 * 16; c += 256) {
        int row = c >> 4, p = c & 15;
        int node = n0 + row;
        uint4 v = {0, 0, 0, 0};
        if (node < N) v = *(const uint4*)(h16 + (size_t)node * HD + p * 8);
        *(uint4*)(xs + row * NST + p * 8) = v;
    }
    for (int c = tid; c < 32 * 32; c += 256) {       // agg: float4 read+zero, half4 stage
        int row = c >> 5, q = c & 31;
        int node = n0 + row;
        float4 v = {0, 0, 0, 0};
        float di = 0.f;
        if (node < N) {
            size_t gi = (size_t)node * HD + q * 4;
            v = *(float4*)(aggsum + gi);
            *(float4*)(aggsum + gi) = make_float4(0.f, 0.f, 0.f, 0.f);
            di = deginv[node];
        }
        half4 o;
        o[0] = (_Float16)(v.x * di); o[1] = (_Float16)(v.y * di);
        o[2] = (_Float16)(v.z * di); o[3] = (_Float16)(v.w * di);
        *(half4*)(xs + row * NST + HD + q * 4) = o;
    }
    __syncthreads();

    int lane = tid & 63, wv = tid >> 6;
    int l31 = lane & 31, lh = lane >> 5;
    int nc  = wv * 32 + l31;                 // lane's single output col for GEMM1/2

    floatx16 acc0 = {};
    {
        const _Float16* ap  = xs  + (size_t)l31 * NST + lh * 8;
        const _Float16* bp0 = W1T + (size_t)nc * 256 + lh * 8;
        for (int ks = 0; ks < 16; ++ks) {
            half8 a = *(const half8*)(ap + ks * 16);
            acc0 = __builtin_amdgcn_mfma_f32_32x32x16_f16(a, *(const half8*)(bp0 + ks * 16), acc0, 0, 0, 0);
        }
    }
    __syncthreads();
    {
        float b10 = b1[nc];
        #pragma unroll
        for (int r = 0; r < 16; ++r) {
            int row = (r & 3) + 8 * (r >> 2) + 4 * lh;
            x1s[row * XST + nc] = (_Float16)silu_f(acc0[r] + b10);
        }
    }
    __syncthreads();

    acc0 = {};
    {
        const _Float16* ap  = x1s + (size_t)l31 * XST + lh * 8;
        const _Float16* bp0 = W2T + (size_t)nc * HD + lh * 8;
        for (int ks = 0; ks < 8; ++ks) {
            half8 a = *(const half8*)(ap + ks * 16);
            acc0 = __builtin_amdgcn_mfma_f32_32x32x16_f16(a, *(const half8*)(bp0 + ks * 16), acc0, 0, 0, 0);
        }
    }
    __syncthreads();   // all waves done reading x1s before restage

    {
        float b20 = b2[nc];
        #pragma unroll
        for (int r = 0; r < 16; ++r) {
            int row = (r & 3) + 8 * (r >> 2) + 4 * lh;
            int node = n0 + row;
            float v0 = silu_f(acc0[r] + b20);
            _Float16 hv;
            if (node < N) {
                size_t g0 = (size_t)node * HD + nc;
                v0 += h[g0];
                h[g0] = v0;
                hv = (_Float16)v0;
                h16[g0] = hv;
            } else hv = (_Float16)0.f;
            xs[row * PST + nc] = hv;
        }
    }
    __syncthreads();

    // next-layer P/Q: waves 0,1 -> P cols 0/64; waves 2,3 -> Q cols 0/64 (interleaved pairs)
    {
        const _Float16* BT  = (wv >> 1) ? WbT : WaT;
        _Float16*       OUT = (wv >> 1) ? Q16 : P16;
        int cbq = 64 * (wv & 1);
        int c0  = cbq + 2 * l31;
        floatx16 a0 = {}, a1 = {};
        const _Float16* ap  = xs + (size_t)l31 * PST + lh * 8;
        const _Float16* bp0 = BT + (size_t)c0 * HD + lh * 8;
        const _Float16* bp1 = BT + (size_t)(c0 + 1) * HD + lh * 8;
        for (int ks = 0; ks < 8; ++ks) {
            half8 a = *(const half8*)(ap + ks * 16);
            a0 = __builtin_amdgcn_mfma_f32_32x32x16_f16(a, *(const half8*)(bp0 + ks * 16), a0, 0, 0, 0);
            a1 = __builtin_amdgcn_mfma_f32_32x32x16_f16(a, *(const half8*)(bp1 + ks * 16), a1, 0, 0, 0);
        }
        #pragma unroll
        for (int r = 0; r < 16; ++r) {
            int row = (r & 3) + 8 * (r >> 2) + 4 * lh;
            int node = n0 + row;
            if (node < N) {
                half2v o; o[0] = (_Float16)a0[r]; o[1] = (_Float16)a1[r];
                *(half2v*)(OUT + (size_t)node * HD + c0) = o;
            }
        }
    }
}

// ---------------- launcher ----------------
extern "C" void kernel_launch(void* const* d_in, const int* in_sizes, int n_in,
                              void* d_out, int out_size, void* d_ws, size_t ws_size,
                              hipStream_t stream)
{
    const int*   at    = (const int*)  d_in[0];
    const float* t     = (const float*)d_in[1];
    const float* fc    = (const float*)d_in[2];
    const int*   ei    = (const int*)  d_in[3];
    const float* lat   = (const float*)d_in[4];
    const int*   n2g   = (const int*)  d_in[5];
    const float* embed = (const float*)d_in[6];
    const float* lat_w = (const float*)d_in[7];
    const float* lat_b = (const float*)d_in[8];
    const float* ew1   = (const float*)d_in[9];
    const float* eb1   = (const float*)d_in[10];
    const float* ew2   = (const float*)d_in[11];
    const float* eb2   = (const float*)d_in[12];
    const float* nw1   = (const float*)d_in[13];
    const float* nb1   = (const float*)d_in[14];
    const float* nw2   = (const float*)d_in[15];
    const float* nb2   = (const float*)d_in[16];
    const float* cw1   = (const float*)d_in[17];
    const float* cb1   = (const float*)d_in[18];
    const float* cw2   = (const float*)d_in[19];

    int N = in_sizes[0];
    int E = in_sizes[3] / 2;
    int G = in_sizes[4] / 9;

    // ---- workspace carve ----
    char* p = (char*)d_ws;
    float* h      = (float*)p;  p += (size_t)N * HD * 4;
    float* aggsum = (float*)p;  p += (size_t)N * HD * 4;   // zeroed below
    float* outsum = (float*)p;  p += (size_t)N * 3 * 4;    // zeroed below
    int*   cnt    = (int*)p;    p += (size_t)N * 4;        // zeroed below
    int*   head   = (int*)p;    p += (size_t)N * 4;
    float* deginv = (float*)p;  p += (size_t)N * 4;
    float* latip  = (float*)p;  p += (size_t)G * 9 * 4;
    int*   perm   = (int*)p;    p += (size_t)E * 4;
    int*   eaS    = (int*)p;    p += (size_t)E * 4;
    int*   ebS    = (int*)p;    p += (size_t)E * 4;
    int*   egS    = (int*)p;    p += (size_t)E * 4;
    float* fdS    = (float*)p;  p += (size_t)E * 3 * 4;
    _Float16* h16   = (_Float16*)p; p += (size_t)N * HD * 2;
    _Float16* P16   = (_Float16*)p; p += (size_t)N * HD * 2;
    _Float16* Q16   = (_Float16*)p; p += (size_t)N * HD * 2;
    _Float16* w1aT  = (_Float16*)p; p += (size_t)4 * HD * HD * 2;
    _Float16* w1bT  = (_Float16*)p; p += (size_t)4 * HD * HD * 2;
    _Float16* wdT   = (_Float16*)p; p += (size_t)4 * HD * 64 * 2;
    _Float16* w2T   = (_Float16*)p; p += (size_t)4 * HD * HD * 2;
    _Float16* nw1T  = (_Float16*)p; p += (size_t)3 * HD * 256 * 2;
    _Float16* nw2T  = (_Float16*)p; p += (size_t)3 * HD * HD * 2;
    _Float16* cw1T  = (_Float16*)p; p += (size_t)HD * HD * 2;
    _Float16* latwT = (_Float16*)p; p += (size_t)HD * 400 * 2;
    _Float16* R16   = (_Float16*)p; p += (size_t)4 * G * HD * 2;

    // zero aggsum|outsum|cnt (contiguous)
    hipMemsetAsync(aggsum, 0, ((size_t)N * HD + (size_t)N * 3 + N) * 4, stream);

    // weight prep (fp16, transposed, K-padded)
    {
        int tot;
        tot = 4 * HD * HD;  k_wprep<<<(tot+255)/256, 256, 0, stream>>>(ew1, w1aT, EIN, 0,   128, HD, HD, 4);
        tot = 4 * HD * HD;  k_wprep<<<(tot+255)/256, 256, 0, stream>>>(ew1, w1bT, EIN, 128, 128, HD, HD, 4);
        tot = 4 * HD * 64;  k_wprep<<<(tot+255)/256, 256, 0, stream>>>(ew1, wdT,  EIN, 265, 60,  HD, 64, 4);
        tot = 4 * HD * HD;  k_wprep<<<(tot+255)/256, 256, 0, stream>>>(ew2, w2T,  HD,  0,  128, HD, HD, 4);
        tot = 3 * HD * 256; k_wprep<<<(tot+255)/256, 256, 0, stream>>>(nw1, nw1T, 256, 0,  256, HD, 256, 3);
        tot = 3 * HD * HD;  k_wprep<<<(tot+255)/256, 256, 0, stream>>>(nw2, nw2T, HD,  0,  128, HD, HD, 3);
        tot = 1 * HD * HD;  k_wprep<<<(tot+255)/256, 256, 0, stream>>>(cw1, cw1T, HD,  0,  128, HD, HD, 1);
        tot = HD * 400;     k_wprep<<<(tot+255)/256, 256, 0, stream>>>(lat_w, latwT, 384, 0, 384, HD, 400, 1);
    }

    k_latip  <<<(G * 9 + 255) / 256, 256, 0, stream>>>(lat, latip, G);
    k_hist   <<<(E + 255) / 256,     256, 0, stream>>>(ei + E, cnt, E);
    k_scan   <<<1, 1024, 0, stream>>>(cnt, head, N);
    k_deginv <<<(N + 255) / 256,     256, 0, stream>>>(cnt, deginv, N);
    k_scatter<<<(E + 255) / 256,     256, 0, stream>>>(ei + E, head, perm, E);
    k_esort  <<<(E + 255) / 256,     256, 0, stream>>>(ei, n2g, fc, perm, eaS, ebS, egS, fdS, E);
    k_rlat   <<<(4 * G * HD + 255) / 256, 256, 0, stream>>>(latip, ew1, eb1, R16, G);
    k_init_pq<<<(N + 63) / 64, 256, 0, stream>>>(at, t, embed, latwT, lat_b, h, h16,
                                                 w1aT, w1bT, P16, Q16, N);

    int eblocks = (E + 31) / 32;            // one 32-edge tile per 128-thread block
    int nblocks = (N + 31) / 32;
    for (int l = 0; l < 3; ++l) {
        k_edge<false><<<eblocks, 128, 0, stream>>>(eaS, ebS, egS, fdS, P16, Q16,
            R16 + (size_t)l * G * HD, wdT + (size_t)l * HD * 64,
            w2T + (size_t)l * HD * HD, eb2 + l * HD,
            cw1T, cb1, cw2, aggsum, outsum, E);
        k_node_pq<<<nblocks, 256, 0, stream>>>(h, h16, aggsum, deginv,
            nw1T + (size_t)l * HD * 256, nb1 + l * HD,
            nw2T + (size_t)l * HD * HD,  nb2 + l * HD,
            w1aT + (size_t)(l + 1) * HD * HD, w1bT + (size_t)(l + 1) * HD * HD,
            P16, Q16, N);
    }
    k_edge<true><<<eblocks, 128, 0, stream>>>(eaS, ebS, egS, fdS, P16, Q16,
        R16 + (size_t)3 * G * HD, wdT + (size_t)3 * HD * 64,
        w2T + (size_t)3 * HD * HD, eb2 + 3 * HD,
        cw1T, cb1, cw2, aggsum, outsum, E);

    k_fin<<<(N * 3 + 255) / 256, 256, 0, stream>>>(outsum, deginv, (float*)d_out, N);
}

// Round 9
// 528.397 us; speedup vs baseline: 1.2363x; 1.2363x over previous
//
#include <hip/hip_runtime.h>
#include <hip/hip_bf16.h>
#include <hip/hip_fp16.h>
#include <math.h>

#define HD    128
#define EIN   325
#define PST   136      // edge tile row stride (f16), 16B-aligned
#define DST   72       // dis feature row stride (f16): 144B rows, 16B-aligned
#define NST   264      // node A-tile row stride (f16)
#define XST   136      // node x1 tile row stride
#define IST   408      // init A-tile row stride (400+8)

typedef _Float16 half8 __attribute__((ext_vector_type(8)));
typedef _Float16 half4 __attribute__((ext_vector_type(4)));
typedef _Float16 half2v __attribute__((ext_vector_type(2)));
typedef float    floatx16 __attribute__((ext_vector_type(16)));

// intra-wave LDS RAW fence (cross-lane write->read). Also a compiler memory fence.
#define WSYNC() __asm__ volatile("s_waitcnt lgkmcnt(0)" ::: "memory")

// fast silu: v_exp + v_rcp (approx) instead of IEEE div sequence
__device__ __forceinline__ float silu_f(float x) {
    return x * __builtin_amdgcn_rcpf(1.0f + __expf(-x));
}

// ---- generic weight prep: fp32 [m][Ktot][Nn] rows [krow0, krow0+Kact) -> fp16 [m][Nn][Kpad]
__global__ void k_wprep(const float* __restrict__ src, _Float16* __restrict__ dst,
                        int Ktot, int krow0, int Kact, int Nn, int Kpad, int nmat) {
    int idx = blockIdx.x * 256 + threadIdx.x;
    int per = Nn * Kpad;
    if (idx >= nmat * per) return;
    int m = idx / per, r = idx - m * per;
    int n = r / Kpad, k = r - n * Kpad;
    float v = (k < Kact) ? src[(size_t)m * Ktot * Nn + (size_t)(krow0 + k) * Nn + n] : 0.f;
    dst[idx] = (_Float16)v;
}

// ---- fragment-order weight prep for k_edge's B operands ----
// Blob layout: [m][ks*4+i][lane][8], lane = l31 + 32*lh, col = 4*l31 + i,
// k = 16*ks + 8*lh + j. Each wave64 load of instruction (ks,i) is 1KB contiguous.
__global__ void k_wfrag(const float* __restrict__ src, _Float16* __restrict__ dst,
                        int Ktot, int krow0, int Kact, int nks, int nmat) {
    int idx = blockIdx.x * 256 + threadIdx.x;
    int per = nks * 2048;                       // nks * 4 * 64 * 8
    if (idx >= nmat * per) return;
    int m = idx / per, r = idx - m * per;
    int j    = r & 7;
    int lane = (r >> 3) & 63;
    int blk  = r >> 9;                          // ks*4 + i
    int ks = blk >> 2, i = blk & 3;
    int l31 = lane & 31, lh = lane >> 5;
    int col = 4 * l31 + i;
    int k   = 16 * ks + 8 * lh + j;
    float v = (k < Kact) ? src[(size_t)m * Ktot * HD + (size_t)(krow0 + k) * HD + col] : 0.f;
    dst[idx] = (_Float16)v;
}

// ---- tiny kernels ----
__global__ void k_latip(const float* __restrict__ lat, float* __restrict__ latip, int G) {
    int idx = blockIdx.x * 256 + threadIdx.x;
    if (idx >= G * 9) return;
    int g = idx / 9, ij = idx - g * 9, i = ij / 3, k = ij - (ij / 3) * 3;
    const float* L = lat + g * 9;
    latip[idx] = L[i*3+0]*L[k*3+0] + L[i*3+1]*L[k*3+1] + L[i*3+2]*L[k*3+2];
}

__global__ void k_hist(const int* __restrict__ ei1, int* __restrict__ cnt, int E) {
    int idx = blockIdx.x * 256 + threadIdx.x;
    if (idx < E) atomicAdd(&cnt[ei1[idx]], 1);
}

__global__ void k_deginv(const int* __restrict__ cnt, float* __restrict__ deginv, int N) {
    int idx = blockIdx.x * 256 + threadIdx.x;
    if (idx < N) deginv[idx] = 1.0f / fmaxf((float)cnt[idx], 1.0f);
}

__global__ __launch_bounds__(1024) void k_scan(const int* __restrict__ cnt,
                                               int* __restrict__ head, int N) {
    __shared__ int part[1024];
    int tid = threadIdx.x;
    int chunk = (N + 1023) >> 10;
    int start = tid * chunk, stop = min(start + chunk, N);
    int s = 0;
    for (int i = start; i < stop; ++i) s += cnt[i];
    part[tid] = s;
    __syncthreads();
    for (int off = 1; off < 1024; off <<= 1) {
        int v = (tid >= off) ? part[tid - off] : 0;
        __syncthreads();
        part[tid] += v;
        __syncthreads();
    }
    int run = (tid > 0) ? part[tid - 1] : 0;
    for (int i = start; i < stop; ++i) { head[i] = run; run += cnt[i]; }
}

__global__ void k_scatter(const int* __restrict__ ei1, int* __restrict__ head,
                          int* __restrict__ perm, int E) {
    int e = blockIdx.x * 256 + threadIdx.x;
    if (e < E) {
        int d = ei1[e];
        int pos = atomicAdd(&head[d], 1);
        perm[pos] = e;
    }
}

// ---- sorted edge meta (dis features computed in-kernel in k_edge) ----
__global__ void k_esort(const int* __restrict__ ei, const int* __restrict__ n2g,
                        const float* __restrict__ fc, const int* __restrict__ perm,
                        int* __restrict__ eaS, int* __restrict__ ebS, int* __restrict__ egS,
                        float* __restrict__ fdS, int E) {
    int s = blockIdx.x * 256 + threadIdx.x;
    if (s >= E) return;
    int e = perm[s];
    int a = ei[e], b = ei[E + e];
    eaS[s] = a; ebS[s] = b; egS[s] = n2g[a];
    #pragma unroll
    for (int d = 0; d < 3; ++d) {
        float sh = fc[b * 3 + d] - fc[a * 3 + d];
        fdS[s * 3 + d] = sh - floorf(sh + 0.5f + 1e-4f);
    }
}

// ---- per-graph table: R[l][g][c] = latip[g] @ W1lat[l] + eb1[l] ----
__global__ void k_rlat(const float* __restrict__ latip, const float* __restrict__ ew1,
                       const float* __restrict__ eb1, _Float16* __restrict__ R16, int G) {
    int idx = blockIdx.x * 256 + threadIdx.x;
    if (idx >= 4 * G * HD) return;
    int l = idx / (G * HD), r = idx - l * (G * HD), g = r >> 7, c = r & 127;
    const float* W  = ew1 + (size_t)l * EIN * HD + 256 * HD;  // k-rows 256..264
    const float* lp = latip + g * 9;
    float s = eb1[l * HD + c];
    #pragma unroll
    for (int j = 0; j < 9; ++j) s = fmaf(lp[j], W[j * HD + c], s);
    R16[idx] = (_Float16)s;
}

__global__ void k_fin(const float* __restrict__ outsum, const float* __restrict__ deginv,
                      float* __restrict__ out, int N) {
    int idx = blockIdx.x * 256 + threadIdx.x;
    if (idx < N * 3) out[idx] = outsum[idx] * deginv[idx / 3];
}

// ---- node init fused with first P/Q ----
__global__ __launch_bounds__(256) void k_init_pq(
    const int* __restrict__ at, const float* __restrict__ t,
    const float* __restrict__ embed, const _Float16* __restrict__ latwT,
    const float* __restrict__ lat_b, float* __restrict__ h,
    _Float16* __restrict__ h16,
    const _Float16* __restrict__ WaT, const _Float16* __restrict__ WbT,
    _Float16* __restrict__ P16, _Float16* __restrict__ Q16, int N)
{
    __shared__ __align__(16) _Float16 xs[64 * IST];   // 51 KB
    __shared__ int   atL[64];
    __shared__ float tL[64];
    __shared__ float frL[128];
    int tid = threadIdx.x;
    int n0  = blockIdx.x * 64;

    if (tid < 64) {
        int node = n0 + tid;
        atL[tid] = (node < N) ? at[node] - 1 : 0;
        tL[tid]  = (node < N) ? t[node] : 0.f;
    }
    if (tid < 128) frL[tid] = __expf(-(float)tid * 0.07252236514f);
    __syncthreads();

    for (int c = tid; c < 64 * 32; c += 256) {       // embed cols 0..127
        int row = c >> 5, p = c & 31;
        float4 v = {0, 0, 0, 0};
        if (n0 + row < N) v = *(const float4*)(embed + (size_t)atL[row] * HD + p * 4);
        _Float16* d = xs + row * IST + p * 4;
        d[0] = (_Float16)v.x; d[1] = (_Float16)v.y; d[2] = (_Float16)v.z; d[3] = (_Float16)v.w;
    }
    for (int c = tid; c < 64 * 272; c += 256) {      // sin/cos cols 128..383 + pad
        int row = c / 272, j = c - row * 272;
        float v = 0.f;
        if (j < 256 && n0 + row < N) {
            int k = j & 127;
            float a = tL[row] * frL[k];
            v = (j < 128) ? __sinf(a) : __cosf(a);
        }
        xs[row * IST + 128 + j] = (_Float16)v;
    }
    __syncthreads();

    int lane = tid & 63, wv = tid >> 6;
    int l31 = lane & 31, lh = lane >> 5;
    int rm = (wv >> 1) * 32, cb = (wv & 1) * 64;
    int n0c = cb + 2 * l31, n1c = n0c + 1;           // interleaved col ownership

    floatx16 acc0 = {}, acc1 = {};
    {
        const _Float16* ap  = xs + (size_t)(rm + l31) * IST + lh * 8;
        const _Float16* bp0 = latwT + (size_t)n0c * 400 + lh * 8;
        const _Float16* bp1 = latwT + (size_t)n1c * 400 + lh * 8;
        for (int ks = 0; ks < 25; ++ks) {
            half8 a  = *(const half8*)(ap  + ks * 16);
            acc0 = __builtin_amdgcn_mfma_f32_32x32x16_f16(a, *(const half8*)(bp0 + ks * 16), acc0, 0, 0, 0);
            acc1 = __builtin_amdgcn_mfma_f32_32x32x16_f16(a, *(const half8*)(bp1 + ks * 16), acc1, 0, 0, 0);
        }
    }
    __syncthreads();   // all waves done reading xs A-tile

    {
        float2 bb = *(const float2*)(lat_b + n0c);
        #pragma unroll
        for (int r = 0; r < 16; ++r) {
            int row = rm + (r & 3) + 8 * (r >> 2) + 4 * lh;
            int node = n0 + row;
            float v0 = acc0[r] + bb.x, v1 = acc1[r] + bb.y;
            half2v h2; h2[0] = (_Float16)v0; h2[1] = (_Float16)v1;
            if (node < N) {
                *(float2*)(h + (size_t)node * HD + n0c) = make_float2(v0, v1);
                *(half2v*)(h16 + (size_t)node * HD + n0c) = h2;
            }
            *(half2v*)(xs + row * PST + n0c) = h2;   // stage for PQ GEMMs
        }
    }
    __syncthreads();

    // P/Q GEMMs: wave wv&1 selects matrix; cols 4*l31+i (adjacent quad per lane)
    {
        const _Float16* BT  = (wv & 1) ? WbT : WaT;
        _Float16*       OUT = (wv & 1) ? Q16 : P16;
        floatx16 acc[4] = {};
        const _Float16* ap = xs + (size_t)(rm + l31) * PST + lh * 8;
        for (int ks = 0; ks < 8; ++ks) {
            half8 a = *(const half8*)(ap + ks * 16);
            #pragma unroll
            for (int i = 0; i < 4; ++i) {
                half8 b = *(const half8*)(BT + (size_t)(4 * l31 + i) * HD + ks * 16 + lh * 8);
                acc[i] = __builtin_amdgcn_mfma_f32_32x32x16_f16(a, b, acc[i], 0, 0, 0);
            }
        }
        #pragma unroll
        for (int r = 0; r < 16; ++r) {
            int row = rm + (r & 3) + 8 * (r >> 2) + 4 * lh;
            int node = n0 + row;
            if (node < N) {
                half4 o;
                #pragma unroll
                for (int i = 0; i < 4; ++i) o[i] = (_Float16)acc[i][r];
                *(half4*)(OUT + (size_t)node * HD + 4 * l31) = o;
            }
        }
    }
}

// ---- fused edge kernel: WAVE-OWNED 32-edge tiles, ZERO __syncthreads ----
// dis features computed IN-KERNEL into the wave-private LDS tile; af[4] read back
// as ds_read_b128 in A-fragment order; PQR staging overwrites the region.
// Weight B operands in FRAGMENT-ORDER blobs: instruction (ks,i) reads 1KB
// contiguous (lane*16B) -> fully coalesced, 16 lines/instr, zero waste.
template <bool LAST>
__global__ __launch_bounds__(256, 4) void k_edge(
    const int* __restrict__ eaS, const int* __restrict__ ebS,
    const int* __restrict__ egS, const float* __restrict__ fdS,
    const _Float16* __restrict__ P16, const _Float16* __restrict__ Q16,
    const _Float16* __restrict__ R16, const _Float16* __restrict__ WdT,
    const _Float16* __restrict__ W2T, const float* __restrict__ b2,
    const _Float16* __restrict__ cw1T, const float* __restrict__ cb1,
    const float* __restrict__ cw2,
    float* __restrict__ aggsum, float* __restrict__ outsum, int E)
{
    __shared__ __align__(16) _Float16 xt[4][32 * PST];  // 4 x 8.7 KB, wave-private
    __shared__ int   eaW[4][32], ebW[4][32], egW[4][32];
    __shared__ float fdW[LAST ? 4 : 1][32][3];
    __shared__ float gateW[LAST ? 4 : 1][32];

    int tid  = threadIdx.x;
    int wv   = tid >> 6, lane = tid & 63;
    int l31  = lane & 31, lh = lane >> 5;
    int s0   = blockIdx.x * 128 + wv * 32;

    _Float16* XT  = xt[wv];
    int* eaw = eaW[wv];
    int* ebw = ebW[wv];
    int* egw = egW[wv];

    // fragment-order weight bases (lane-contiguous)
    const _Float16* bwd = WdT  + (size_t)lane * 8;
    const _Float16* bw2 = W2T  + (size_t)lane * 8;

    // ---- wave-private meta stage
    if (lane < 32) {
        int s = s0 + lane;
        int a = 0, b = -1, g = 0;
        if (s < E) { a = eaS[s]; b = ebS[s]; g = egS[s]; }
        eaw[lane] = a; ebw[lane] = b; egw[lane] = g;
        if (LAST) {
            float f0 = 0.f, f1 = 0.f, f2 = 0.f;
            if (s < E) { f0 = fdS[s*3]; f1 = fdS[s*3+1]; f2 = fdS[s*3+2]; }
            fdW[wv][lane][0] = f0; fdW[wv][lane][1] = f1; fdW[wv][lane][2] = f2;
        }
    }

    // ---- in-wave dis feature build into XT as [32][DST] ----
    // Lane (l31, lh): edge s0+l31; lh=0 computes sin side (k=10d+w), lh=1 cos
    // side (k=30+10d+w) via the Chebyshev recurrence m_w = 2c1*m_{w-1} - m_{w-2}.
    {
        int s = s0 + l31;
        float fd3[3] = {0.f, 0.f, 0.f};
        if (s < E) { fd3[0] = fdS[s*3]; fd3[1] = fdS[s*3+1]; fd3[2] = fdS[s*3+2]; }
        _Float16* dr = XT + l31 * DST + lh * 30;
        #pragma unroll
        for (int d = 0; d < 3; ++d) {
            float ang = 6.283185307179586f * fd3[d];
            float s1 = __sinf(ang), c1 = __cosf(ang);
            float tc = 2.f * c1;
            float m2 = lh ? 1.f : 0.f;       // w=0: cos=1, sin=0
            float m1 = lh ? c1  : s1;        // w=1
            half2v h01; h01[0] = (_Float16)m2; h01[1] = (_Float16)m1;
            *(half2v*)(dr + 10 * d) = h01;
            #pragma unroll
            for (int w = 2; w < 10; w += 2) {
                float a0 = tc * m1 - m2;
                float a1 = tc * a0 - m1;
                half2v hh; hh[0] = (_Float16)a0; hh[1] = (_Float16)a1;
                *(half2v*)(dr + 10 * d + w) = hh;
                m2 = a0; m1 = a1;
            }
        }
        // k = 60..63 zero pad (both halves write same value -> benign)
        half2v z; z[0] = (_Float16)0.f; z[1] = (_Float16)0.f;
        *(half2v*)(XT + l31 * DST + 60) = z;
        *(half2v*)(XT + l31 * DST + 62) = z;
    }
    WSYNC();                                         // dis + meta visible

    // ---- af[4] from LDS in A-fragment order (k = 16ks + 8lh + j)
    half8 af[4];
    {
        const _Float16* dp = XT + l31 * DST + lh * 8;
        af[0] = *(const half8*)(dp);      af[1] = *(const half8*)(dp + 16);
        af[2] = *(const half8*)(dp + 32); af[3] = *(const half8*)(dp + 48);
    }
    WSYNC();                                         // reads drained before overwrite

    // ---- gather + stage PQR tile (32 rows x 128 cols)
    #pragma unroll 4
    for (int k = 0; k < 8; ++k) {
        int c   = lane + 64 * k;
        int row = c >> 4, p8 = (c & 15) * 8;
        int a = eaw[row];
        int b = ebw[row]; if (b < 0) b = 0;
        int g = egw[row];
        half8 pv = *(const half8*)(P16 + (size_t)a * HD + p8);
        half8 qv = *(const half8*)(Q16 + (size_t)b * HD + p8);
        half8 rv = *(const half8*)(R16 + (size_t)g * HD + p8);
        *(half8*)(XT + row * PST + p8) = pv + qv + rv;
    }

    // ---- dis GEMM: K = 64, A from regs, 4 col-quads (cols 4*l31+i), frag-order B
    floatx16 acc[4] = {};
    #pragma unroll
    for (int ks = 0; ks < 4; ++ks) {
        #pragma unroll
        for (int i = 0; i < 4; ++i) {
            half8 b = *(const half8*)(bwd + (((ks << 2) | i) << 9));
            acc[i] = __builtin_amdgcn_mfma_f32_32x32x16_f16(af[ks], b, acc[i], 0, 0, 0);
        }
    }
    WSYNC();                                         // staging writes drained

    // ---- x1 = silu(accD + PQR), lane-owned half4 (cols 4*l31..+3)
    #pragma unroll
    for (int r = 0; r < 16; ++r) {
        int row = (r & 3) + 8 * (r >> 2) + 4 * lh;
        half4 pq = *(const half4*)(XT + row * PST + 4 * l31);
        half4 o;
        #pragma unroll
        for (int i = 0; i < 4; ++i)
            o[i] = (_Float16)silu_f(acc[i][r] + (float)pq[i]);
        *(half4*)(XT + row * PST + 4 * l31) = o;
    }
    WSYNC();                                         // x1 visible

    // ---- GEMM2: ef = silu(x1 @ W2 + b2), K = 128, frag-order B
    #pragma unroll
    for (int i = 0; i < 4; ++i) acc[i] = (floatx16){};
    for (int ks = 0; ks < 8; ++ks) {
        half8 a = *(const half8*)(XT + (size_t)l31 * PST + ks * 16 + lh * 8);
        #pragma unroll
        for (int i = 0; i < 4; ++i) {
            half8 b = *(const half8*)(bw2 + (((ks << 2) | i) << 9));
            acc[i] = __builtin_amdgcn_mfma_f32_32x32x16_f16(a, b, acc[i], 0, 0, 0);
        }
    }
    {
        float4 b2v = *(const float4*)(b2 + 4 * l31);
        #pragma unroll
        for (int r = 0; r < 16; ++r) {
            int row = (r & 3) + 8 * (r >> 2) + 4 * lh;
            half4 o;
            o[0] = (_Float16)silu_f(acc[0][r] + b2v.x);
            o[1] = (_Float16)silu_f(acc[1][r] + b2v.y);
            o[2] = (_Float16)silu_f(acc[2][r] + b2v.z);
            o[3] = (_Float16)silu_f(acc[3][r] + b2v.w);
            *(half4*)(XT + row * PST + 4 * l31) = o;
        }
    }
    WSYNC();                                         // ef visible

    if (!LAST) {
        // ---- run-reduced scatter (edges sorted by dest), lane owns col pair
        int c2 = lane * 2;
        float sx = 0.f, sy = 0.f;
        int cur = -1;
        for (int r = 0; r < 32; ++r) {
            int d = ebw[r];
            half2v v = *(const half2v*)(XT + r * PST + c2);
            float vx = (float)v[0], vy = (float)v[1];
            if (d != cur) {
                if (cur >= 0) {
                    atomicAdd(&aggsum[(size_t)cur * HD + c2],     sx);
                    atomicAdd(&aggsum[(size_t)cur * HD + c2 + 1], sy);
                }
                cur = d; sx = vx; sy = vy;
            } else { sx += vx; sy += vy; }
        }
        if (cur >= 0) {
            atomicAdd(&aggsum[(size_t)cur * HD + c2],     sx);
            atomicAdd(&aggsum[(size_t)cur * HD + c2 + 1], sy);
        }
    } else {
        // ---- GEMM3: g1 = silu(ef @ cw1 + cb1); gate = g1 @ cw2, frag-order B
        const _Float16* bw3 = cw1T + (size_t)lane * 8;
        #pragma unroll
        for (int i = 0; i < 4; ++i) acc[i] = (floatx16){};
        for (int ks = 0; ks < 8; ++ks) {
            half8 a = *(const half8*)(XT + (size_t)l31 * PST + ks * 16 + lh * 8);
            #pragma unroll
            for (int i = 0; i < 4; ++i) {
                half8 b = *(const half8*)(bw3 + (((ks << 2) | i) << 9));
                acc[i] = __builtin_amdgcn_mfma_f32_32x32x16_f16(a, b, acc[i], 0, 0, 0);
            }
        }
        float4 cbv = *(const float4*)(cb1 + 4 * l31);
        float4 wv4 = *(const float4*)(cw2 + 4 * l31);
        #pragma unroll
        for (int r = 0; r < 16; ++r) {
            float p = silu_f(acc[0][r] + cbv.x) * wv4.x
                    + silu_f(acc[1][r] + cbv.y) * wv4.y
                    + silu_f(acc[2][r] + cbv.z) * wv4.z
                    + silu_f(acc[3][r] + cbv.w) * wv4.w;
            p += __shfl_xor(p, 16);
            p += __shfl_xor(p, 8);
            p += __shfl_xor(p, 4);
            p += __shfl_xor(p, 2);
            p += __shfl_xor(p, 1);
            if (l31 == 0) {
                int row = (r & 3) + 8 * (r >> 2) + 4 * lh;
                gateW[wv][row] = p;                  // lanes 0 & 32 -> distinct rows
            }
        }
        WSYNC();                                     // gates visible
        if (lane < 32) {
            int r = lane, d = ebw[r];
            if (d >= 0 && (r == 0 || ebw[r - 1] != d)) {
                float sx = 0.f, sy = 0.f, sz = 0.f;
                for (int q = r; q < 32 && ebw[q] == d; ++q) {
                    float g = gateW[wv][q];
                    sx += fdW[wv][q][0] * g;
                    sy += fdW[wv][q][1] * g;
                    sz += fdW[wv][q][2] * g;
                }
                atomicAdd(&outsum[d * 3 + 0], sx);
                atomicAdd(&outsum[d * 3 + 1], sy);
                atomicAdd(&outsum[d * 3 + 2], sz);
            }
        }
    }
}

// ---- fused node update + next-layer P/Q: 32-row tiles, waves split over columns ----
__global__ __launch_bounds__(256) void k_node_pq(
    float* __restrict__ h, _Float16* __restrict__ h16,
    float* __restrict__ aggsum, const float* __restrict__ deginv,
    const _Float16* __restrict__ W1T, const float* __restrict__ b1,
    const _Float16* __restrict__ W2T, const float* __restrict__ b2,
    const _Float16* __restrict__ WaT, const _Float16* __restrict__ WbT,
    _Float16* __restrict__ P16, _Float16* __restrict__ Q16, int N)
{
    __shared__ __align__(16) _Float16 xs[32 * NST];   // 16.9 KB
    _Float16* x1s = xs;

    int tid = threadIdx.x;
    int n0  = blockIdx.x * 32;

    for (int c = tid; c < 32 * 16; c += 256) {
        int row = c >> 4, p = c & 15;
        int node = n0 + row;
        uint4 v = {0, 0, 0, 0};
        if (node < N) v = *(const uint4*)(h16 + (size_t)node * HD + p * 8);
        *(uint4*)(xs + row * NST + p * 8) = v;
    }
    for (int c = tid; c < 32 * 32; c += 256) {       // agg: float4 read+zero, half4 stage
        int row = c >> 5, q = c & 31;
        int node = n0 + row;
        float4 v = {0, 0, 0, 0};
        float di = 0.f;
        if (node < N) {
            size_t gi = (size_t)node * HD + q * 4;
            v = *(float4*)(aggsum + gi);
            *(float4*)(aggsum + gi) = make_float4(0.f, 0.f, 0.f, 0.f);
            di = deginv[node];
        }
        half4 o;
        o[0] = (_Float16)(v.x * di); o[1] = (_Float16)(v.y * di);
        o[2] = (_Float16)(v.z * di); o[3] = (_Float16)(v.w * di);
        *(half4*)(xs + row * NST + HD + q * 4) = o;
    }
    __syncthreads();

    int lane = tid & 63, wv = tid >> 6;
    int l31 = lane & 31, lh = lane >> 5;
    int nc  = wv * 32 + l31;                 // lane's single output col for GEMM1/2

    floatx16 acc0 = {};
    {
        const _Float16* ap  = xs  + (size_t)l31 * NST + lh * 8;
        const _Float16* bp0 = W1T + (size_t)nc * 256 + lh * 8;
        for (int ks = 0; ks < 16; ++ks) {
            half8 a = *(const half8*)(ap + ks * 16);
            acc0 = __builtin_amdgcn_mfma_f32_32x32x16_f16(a, *(const half8*)(bp0 + ks * 16), acc0, 0, 0, 0);
        }
    }
    __syncthreads();
    {
        float b10 = b1[nc];
        #pragma unroll
        for (int r = 0; r < 16; ++r) {
            int row = (r & 3) + 8 * (r >> 2) + 4 * lh;
            x1s[row * XST + nc] = (_Float16)silu_f(acc0[r] + b10);
        }
    }
    __syncthreads();

    acc0 = {};
    {
        const _Float16* ap  = x1s + (size_t)l31 * XST + lh * 8;
        const _Float16* bp0 = W2T + (size_t)nc * HD + lh * 8;
        for (int ks = 0; ks < 8; ++ks) {
            half8 a = *(const half8*)(ap + ks * 16);
            acc0 = __builtin_amdgcn_mfma_f32_32x32x16_f16(a, *(const half8*)(bp0 + ks * 16), acc0, 0, 0, 0);
        }
    }
    __syncthreads();   // all waves done reading x1s before restage

    {
        float b20 = b2[nc];
        #pragma unroll
        for (int r = 0; r < 16; ++r) {
            int row = (r & 3) + 8 * (r >> 2) + 4 * lh;
            int node = n0 + row;
            float v0 = silu_f(acc0[r] + b20);
            _Float16 hv;
            if (node < N) {
                size_t g0 = (size_t)node * HD + nc;
                v0 += h[g0];
                h[g0] = v0;
                hv = (_Float16)v0;
                h16[g0] = hv;
            } else hv = (_Float16)0.f;
            xs[row * PST + nc] = hv;
        }
    }
    __syncthreads();

    // next-layer P/Q: waves 0,1 -> P cols 0/64; waves 2,3 -> Q cols 0/64 (interleaved pairs)
    {
        const _Float16* BT  = (wv >> 1) ? WbT : WaT;
        _Float16*       OUT = (wv >> 1) ? Q16 : P16;
        int cbq = 64 * (wv & 1);
        int c0  = cbq + 2 * l31;
        floatx16 a0 = {}, a1 = {};
        const _Float16* ap  = xs + (size_t)l31 * PST + lh * 8;
        const _Float16* bp0 = BT + (size_t)c0 * HD + lh * 8;
        const _Float16* bp1 = BT + (size_t)(c0 + 1) * HD + lh * 8;
        for (int ks = 0; ks < 8; ++ks) {
            half8 a = *(const half8*)(ap + ks * 16);
            a0 = __builtin_amdgcn_mfma_f32_32x32x16_f16(a, *(const half8*)(bp0 + ks * 16), a0, 0, 0, 0);
            a1 = __builtin_amdgcn_mfma_f32_32x32x16_f16(a, *(const half8*)(bp1 + ks * 16), a1, 0, 0, 0);
        }
        #pragma unroll
        for (int r = 0; r < 16; ++r) {
            int row = (r & 3) + 8 * (r >> 2) + 4 * lh;
            int node = n0 + row;
            if (node < N) {
                half2v o; o[0] = (_Float16)a0[r]; o[1] = (_Float16)a1[r];
                *(half2v*)(OUT + (size_t)node * HD + c0) = o;
            }
        }
    }
}

// ---------------- launcher ----------------
extern "C" void kernel_launch(void* const* d_in, const int* in_sizes, int n_in,
                              void* d_out, int out_size, void* d_ws, size_t ws_size,
                              hipStream_t stream)
{
    const int*   at    = (const int*)  d_in[0];
    const float* t     = (const float*)d_in[1];
    const float* fc    = (const float*)d_in[2];
    const int*   ei    = (const int*)  d_in[3];
    const float* lat   = (const float*)d_in[4];
    const int*   n2g   = (const int*)  d_in[5];
    const float* embed = (const float*)d_in[6];
    const float* lat_w = (const float*)d_in[7];
    const float* lat_b = (const float*)d_in[8];
    const float* ew1   = (const float*)d_in[9];
    const float* eb1   = (const float*)d_in[10];
    const float* ew2   = (const float*)d_in[11];
    const float* eb2   = (const float*)d_in[12];
    const float* nw1   = (const float*)d_in[13];
    const float* nb1   = (const float*)d_in[14];
    const float* nw2   = (const float*)d_in[15];
    const float* nb2   = (const float*)d_in[16];
    const float* cw1   = (const float*)d_in[17];
    const float* cb1   = (const float*)d_in[18];
    const float* cw2   = (const float*)d_in[19];

    int N = in_sizes[0];
    int E = in_sizes[3] / 2;
    int G = in_sizes[4] / 9;

    // ---- workspace carve ----
    char* p = (char*)d_ws;
    float* h      = (float*)p;  p += (size_t)N * HD * 4;
    float* aggsum = (float*)p;  p += (size_t)N * HD * 4;   // zeroed below
    float* outsum = (float*)p;  p += (size_t)N * 3 * 4;    // zeroed below
    int*   cnt    = (int*)p;    p += (size_t)N * 4;        // zeroed below
    int*   head   = (int*)p;    p += (size_t)N * 4;
    float* deginv = (float*)p;  p += (size_t)N * 4;
    float* latip  = (float*)p;  p += (size_t)G * 9 * 4;
    int*   perm   = (int*)p;    p += (size_t)E * 4;
    int*   eaS    = (int*)p;    p += (size_t)E * 4;
    int*   ebS    = (int*)p;    p += (size_t)E * 4;
    int*   egS    = (int*)p;    p += (size_t)E * 4;
    float* fdS    = (float*)p;  p += (size_t)E * 3 * 4;
    _Float16* h16   = (_Float16*)p; p += (size_t)N * HD * 2;
    _Float16* P16   = (_Float16*)p; p += (size_t)N * HD * 2;
    _Float16* Q16   = (_Float16*)p; p += (size_t)N * HD * 2;
    _Float16* w1aT  = (_Float16*)p; p += (size_t)4 * HD * HD * 2;
    _Float16* w1bT  = (_Float16*)p; p += (size_t)4 * HD * HD * 2;
    _Float16* wdT   = (_Float16*)p; p += (size_t)4 * HD * 64 * 2;
    _Float16* w2T   = (_Float16*)p; p += (size_t)4 * HD * HD * 2;
    _Float16* nw1T  = (_Float16*)p; p += (size_t)3 * HD * 256 * 2;
    _Float16* nw2T  = (_Float16*)p; p += (size_t)3 * HD * HD * 2;
    _Float16* cw1T  = (_Float16*)p; p += (size_t)HD * HD * 2;
    _Float16* latwT = (_Float16*)p; p += (size_t)HD * 400 * 2;
    _Float16* R16   = (_Float16*)p; p += (size_t)4 * G * HD * 2;

    // zero aggsum|outsum|cnt (contiguous)
    hipMemsetAsync(aggsum, 0, ((size_t)N * HD + (size_t)N * 3 + N) * 4, stream);

    // weight prep (fp16; frag-order for k_edge's B operands, transposed for the rest)
    {
        int tot;
        tot = 4 * HD * HD;   k_wprep<<<(tot+255)/256, 256, 0, stream>>>(ew1, w1aT, EIN, 0,   128, HD, HD, 4);
        tot = 4 * HD * HD;   k_wprep<<<(tot+255)/256, 256, 0, stream>>>(ew1, w1bT, EIN, 128, 128, HD, HD, 4);
        tot = 4 * 4 * 2048;  k_wfrag<<<(tot+255)/256, 256, 0, stream>>>(ew1, wdT,  EIN, 265, 60,  4, 4);
        tot = 4 * 8 * 2048;  k_wfrag<<<(tot+255)/256, 256, 0, stream>>>(ew2, w2T,  HD,  0,  128, 8, 4);
        tot = 3 * HD * 256;  k_wprep<<<(tot+255)/256, 256, 0, stream>>>(nw1, nw1T, 256, 0,  256, HD, 256, 3);
        tot = 3 * HD * HD;   k_wprep<<<(tot+255)/256, 256, 0, stream>>>(nw2, nw2T, HD,  0,  128, HD, HD, 3);
        tot = 1 * 8 * 2048;  k_wfrag<<<(tot+255)/256, 256, 0, stream>>>(cw1, cw1T, HD,  0,  128, 8, 1);
        tot = HD * 400;      k_wprep<<<(tot+255)/256, 256, 0, stream>>>(lat_w, latwT, 384, 0, 384, HD, 400, 1);
    }

    k_latip  <<<(G * 9 + 255) / 256, 256, 0, stream>>>(lat, latip, G);
    k_hist   <<<(E + 255) / 256,     256, 0, stream>>>(ei + E, cnt, E);
    k_scan   <<<1, 1024, 0, stream>>>(cnt, head, N);
    k_deginv <<<(N + 255) / 256,     256, 0, stream>>>(cnt, deginv, N);
    k_scatter<<<(E + 255) / 256,     256, 0, stream>>>(ei + E, head, perm, E);
    k_esort  <<<(E + 255) / 256,     256, 0, stream>>>(ei, n2g, fc, perm, eaS, ebS, egS, fdS, E);
    k_rlat   <<<(4 * G * HD + 255) / 256, 256, 0, stream>>>(latip, ew1, eb1, R16, G);
    k_init_pq<<<(N + 63) / 64, 256, 0, stream>>>(at, t, embed, latwT, lat_b, h, h16,
                                                 w1aT, w1bT, P16, Q16, N);

    int eblocks = (E + 127) / 128;
    int nblocks = (N + 31) / 32;
    for (int l = 0; l < 3; ++l) {
        k_edge<false><<<eblocks, 256, 0, stream>>>(eaS, ebS, egS, fdS, P16, Q16,
            R16 + (size_t)l * G * HD, wdT + (size_t)l * HD * 64,
            w2T + (size_t)l * HD * HD, eb2 + l * HD,
            cw1T, cb1, cw2, aggsum, outsum, E);
        k_node_pq<<<nblocks, 256, 0, stream>>>(h, h16, aggsum, deginv,
            nw1T + (size_t)l * HD * 256, nb1 + l * HD,
            nw2T + (size_t)l * HD * HD,  nb2 + l * HD,
            w1aT + (size_t)(l + 1) * HD * HD, w1bT + (size_t)(l + 1) * HD * HD,
            P16, Q16, N);
    }
    k_edge<true><<<eblocks, 256, 0, stream>>>(eaS, ebS, egS, fdS, P16, Q16,
        R16 + (size_t)3 * G * HD, wdT + (size_t)3 * HD * 64,
        w2T + (size_t)3 * HD * HD, eb2 + 3 * HD,
        cw1T, cb1, cw2, aggsum, outsum, E);

    k_fin<<<(N * 3 + 255) / 256, 256, 0, stream>>>(outsum, deginv, (float*)d_out, N);
}

// Round 10
// 499.655 us; speedup vs baseline: 1.3075x; 1.0575x over previous
//
#include <hip/hip_runtime.h>
#include <hip/hip_bf16.h>
#include <hip/hip_fp16.h>
#include <math.h>

#define HD    128
#define EIN   325
#define PST   136      // edge tile row stride (f16), 16B-aligned
#define DST   72       // dis feature row stride (f16): 144B rows, 16B-aligned
#define NST   264      // node A-tile row stride (f16)
#define XST   136      // node x1 tile row stride
#define IST   408      // init A-tile row stride (400+8)

typedef _Float16 half8 __attribute__((ext_vector_type(8)));
typedef _Float16 half4 __attribute__((ext_vector_type(4)));
typedef _Float16 half2v __attribute__((ext_vector_type(2)));
typedef float    floatx16 __attribute__((ext_vector_type(16)));

// intra-wave LDS RAW fence (cross-lane write->read). Also a compiler memory fence.
#define WSYNC() __asm__ volatile("s_waitcnt lgkmcnt(0)" ::: "memory")

// fast silu: v_exp + v_rcp (approx) instead of IEEE div sequence
__device__ __forceinline__ float silu_f(float x) {
    return x * __builtin_amdgcn_rcpf(1.0f + __expf(-x));
}

// ---- unified fragment-order weight prep ----
// Blob: [m][blk][lane][8], blk = ks*4 + sub, lane = l31 + 32*lh, k = 16ks+8lh+j.
// Each wave64 load of one (blk) is 1KB contiguous.
// mode 0: col = 4*l31 + sub            (quad consumers: k_edge B, PQ GEMMs)
// mode 1: col = (sub>>1)*64+2*l31+(sub&1) (pair consumers: init latw)
// mode 2: col = sub*32 + l31           (single-col consumers: node W1/W2)
__global__ void k_wfragU(const float* __restrict__ src, _Float16* __restrict__ dst,
                         int Ktot, int krow0, int Kact, int nks, int nmat, int mode) {
    int idx = blockIdx.x * 256 + threadIdx.x;
    int per = nks * 2048;                       // nks * 4 * 64 * 8
    if (idx >= nmat * per) return;
    int m = idx / per, r = idx - m * per;
    int j    = r & 7;
    int lane = (r >> 3) & 63;
    int blk  = r >> 9;
    int ks = blk >> 2, sub = blk & 3;
    int l31 = lane & 31, lh = lane >> 5;
    int k   = 16 * ks + 8 * lh + j;
    int col;
    if (mode == 0)      col = 4 * l31 + sub;
    else if (mode == 1) col = (sub >> 1) * 64 + 2 * l31 + (sub & 1);
    else                col = sub * 32 + l31;
    float v = (k < Kact) ? src[(size_t)m * Ktot * HD + (size_t)(krow0 + k) * HD + col] : 0.f;
    dst[idx] = (_Float16)v;
}

// ---- tiny kernels ----
__global__ void k_latip(const float* __restrict__ lat, float* __restrict__ latip, int G) {
    int idx = blockIdx.x * 256 + threadIdx.x;
    if (idx >= G * 9) return;
    int g = idx / 9, ij = idx - g * 9, i = ij / 3, k = ij - (ij / 3) * 3;
    const float* L = lat + g * 9;
    latip[idx] = L[i*3+0]*L[k*3+0] + L[i*3+1]*L[k*3+1] + L[i*3+2]*L[k*3+2];
}

__global__ void k_hist(const int* __restrict__ ei1, int* __restrict__ cnt, int E) {
    int idx = blockIdx.x * 256 + threadIdx.x;
    if (idx < E) atomicAdd(&cnt[ei1[idx]], 1);
}

__global__ void k_deginv(const int* __restrict__ cnt, float* __restrict__ deginv, int N) {
    int idx = blockIdx.x * 256 + threadIdx.x;
    if (idx < N) deginv[idx] = 1.0f / fmaxf((float)cnt[idx], 1.0f);
}

__global__ __launch_bounds__(1024) void k_scan(const int* __restrict__ cnt,
                                               int* __restrict__ head, int N) {
    __shared__ int part[1024];
    int tid = threadIdx.x;
    int chunk = (N + 1023) >> 10;
    int start = tid * chunk, stop = min(start + chunk, N);
    int s = 0;
    for (int i = start; i < stop; ++i) s += cnt[i];
    part[tid] = s;
    __syncthreads();
    for (int off = 1; off < 1024; off <<= 1) {
        int v = (tid >= off) ? part[tid - off] : 0;
        __syncthreads();
        part[tid] += v;
        __syncthreads();
    }
    int run = (tid > 0) ? part[tid - 1] : 0;
    for (int i = start; i < stop; ++i) { head[i] = run; run += cnt[i]; }
}

__global__ void k_scatter(const int* __restrict__ ei1, int* __restrict__ head,
                          int* __restrict__ perm, int E) {
    int e = blockIdx.x * 256 + threadIdx.x;
    if (e < E) {
        int d = ei1[e];
        int pos = atomicAdd(&head[d], 1);
        perm[pos] = e;
    }
}

// ---- sorted edge meta (dis features computed in-kernel in k_edge) ----
__global__ void k_esort(const int* __restrict__ ei, const int* __restrict__ n2g,
                        const float* __restrict__ fc, const int* __restrict__ perm,
                        int* __restrict__ eaS, int* __restrict__ ebS, int* __restrict__ egS,
                        float* __restrict__ fdS, int E) {
    int s = blockIdx.x * 256 + threadIdx.x;
    if (s >= E) return;
    int e = perm[s];
    int a = ei[e], b = ei[E + e];
    eaS[s] = a; ebS[s] = b; egS[s] = n2g[a];
    #pragma unroll
    for (int d = 0; d < 3; ++d) {
        float sh = fc[b * 3 + d] - fc[a * 3 + d];
        fdS[s * 3 + d] = sh - floorf(sh + 0.5f + 1e-4f);
    }
}

// ---- per-graph table: R[l][g][c] = latip[g] @ W1lat[l] + eb1[l] ----
__global__ void k_rlat(const float* __restrict__ latip, const float* __restrict__ ew1,
                       const float* __restrict__ eb1, _Float16* __restrict__ R16, int G) {
    int idx = blockIdx.x * 256 + threadIdx.x;
    if (idx >= 4 * G * HD) return;
    int l = idx / (G * HD), r = idx - l * (G * HD), g = r >> 7, c = r & 127;
    const float* W  = ew1 + (size_t)l * EIN * HD + 256 * HD;  // k-rows 256..264
    const float* lp = latip + g * 9;
    float s = eb1[l * HD + c];
    #pragma unroll
    for (int j = 0; j < 9; ++j) s = fmaf(lp[j], W[j * HD + c], s);
    R16[idx] = (_Float16)s;
}

__global__ void k_fin(const float* __restrict__ outsum, const float* __restrict__ deginv,
                      float* __restrict__ out, int N) {
    int idx = blockIdx.x * 256 + threadIdx.x;
    if (idx < N * 3) out[idx] = outsum[idx] * deginv[idx / 3];
}

// ---- node init fused with first P/Q (frag-order weights) ----
__global__ __launch_bounds__(256) void k_init_pq(
    const int* __restrict__ at, const float* __restrict__ t,
    const float* __restrict__ embed, const _Float16* __restrict__ latwF,
    const float* __restrict__ lat_b, float* __restrict__ h,
    _Float16* __restrict__ h16,
    const _Float16* __restrict__ WaF, const _Float16* __restrict__ WbF,
    _Float16* __restrict__ P16, _Float16* __restrict__ Q16, int N)
{
    __shared__ __align__(16) _Float16 xs[64 * IST];   // 51 KB
    __shared__ int   atL[64];
    __shared__ float tL[64];
    __shared__ float frL[128];
    int tid = threadIdx.x;
    int n0  = blockIdx.x * 64;

    if (tid < 64) {
        int node = n0 + tid;
        atL[tid] = (node < N) ? at[node] - 1 : 0;
        tL[tid]  = (node < N) ? t[node] : 0.f;
    }
    if (tid < 128) frL[tid] = __expf(-(float)tid * 0.07252236514f);
    __syncthreads();

    for (int c = tid; c < 64 * 32; c += 256) {       // embed cols 0..127
        int row = c >> 5, p = c & 31;
        float4 v = {0, 0, 0, 0};
        if (n0 + row < N) v = *(const float4*)(embed + (size_t)atL[row] * HD + p * 4);
        _Float16* d = xs + row * IST + p * 4;
        d[0] = (_Float16)v.x; d[1] = (_Float16)v.y; d[2] = (_Float16)v.z; d[3] = (_Float16)v.w;
    }
    for (int c = tid; c < 64 * 272; c += 256) {      // sin/cos cols 128..383 + pad
        int row = c / 272, j = c - row * 272;
        float v = 0.f;
        if (j < 256 && n0 + row < N) {
            int k = j & 127;
            float a = tL[row] * frL[k];
            v = (j < 128) ? __sinf(a) : __cosf(a);
        }
        xs[row * IST + 128 + j] = (_Float16)v;
    }
    __syncthreads();

    int lane = tid & 63, wv = tid >> 6;
    int l31 = lane & 31, lh = lane >> 5;
    int rm = (wv >> 1) * 32, cb = (wv & 1) * 64;
    int n0c = cb + 2 * l31, n1c = n0c + 1;           // interleaved col ownership

    floatx16 acc0 = {}, acc1 = {};
    {
        const _Float16* ap = xs + (size_t)(rm + l31) * IST + lh * 8;
        const _Float16* bp = latwF + (size_t)(wv & 1) * 1024 + lane * 8;  // mode-1 blob
        for (int ks = 0; ks < 25; ++ks) {
            half8 a  = *(const half8*)(ap + ks * 16);
            acc0 = __builtin_amdgcn_mfma_f32_32x32x16_f16(a, *(const half8*)(bp + ks * 2048), acc0, 0, 0, 0);
            acc1 = __builtin_amdgcn_mfma_f32_32x32x16_f16(a, *(const half8*)(bp + ks * 2048 + 512), acc1, 0, 0, 0);
        }
    }
    __syncthreads();   // all waves done reading xs A-tile

    {
        float2 bb = *(const float2*)(lat_b + n0c);
        #pragma unroll
        for (int r = 0; r < 16; ++r) {
            int row = rm + (r & 3) + 8 * (r >> 2) + 4 * lh;
            int node = n0 + row;
            float v0 = acc0[r] + bb.x, v1 = acc1[r] + bb.y;
            half2v h2; h2[0] = (_Float16)v0; h2[1] = (_Float16)v1;
            if (node < N) {
                *(float2*)(h + (size_t)node * HD + n0c) = make_float2(v0, v1);
                *(half2v*)(h16 + (size_t)node * HD + n0c) = h2;
            }
            *(half2v*)(xs + row * PST + n0c) = h2;   // stage for PQ GEMMs
        }
    }
    __syncthreads();

    // P/Q GEMMs: wave wv&1 selects matrix; cols 4*l31+i (mode-0 frag blobs)
    {
        const _Float16* BT  = (wv & 1) ? WbF : WaF;
        _Float16*       OUT = (wv & 1) ? Q16 : P16;
        floatx16 acc[4] = {};
        const _Float16* ap = xs + (size_t)(rm + l31) * PST + lh * 8;
        const _Float16* bp = BT + (size_t)lane * 8;
        for (int ks = 0; ks < 8; ++ks) {
            half8 a = *(const half8*)(ap + ks * 16);
            #pragma unroll
            for (int i = 0; i < 4; ++i) {
                half8 b = *(const half8*)(bp + ks * 2048 + i * 512);
                acc[i] = __builtin_amdgcn_mfma_f32_32x32x16_f16(a, b, acc[i], 0, 0, 0);
            }
        }
        #pragma unroll
        for (int r = 0; r < 16; ++r) {
            int row = rm + (r & 3) + 8 * (r >> 2) + 4 * lh;
            int node = n0 + row;
            if (node < N) {
                half4 o;
                #pragma unroll
                for (int i = 0; i < 4; ++i) o[i] = (_Float16)acc[i][r];
                *(half4*)(OUT + (size_t)node * HD + 4 * l31) = o;
            }
        }
    }
}

// ---- fused edge kernel: WAVE-OWNED 32-edge tiles, ZERO __syncthreads ----
// dis features computed IN-KERNEL into the wave-private LDS tile; af[4] read back
// as ds_read_b128 in A-fragment order; PQR staging overwrites the region.
// Weight B operands in FRAGMENT-ORDER blobs (mode 0): each instr reads 1KB contiguous.
template <bool LAST>
__global__ __launch_bounds__(256, 4) void k_edge(
    const int* __restrict__ eaS, const int* __restrict__ ebS,
    const int* __restrict__ egS, const float* __restrict__ fdS,
    const _Float16* __restrict__ P16, const _Float16* __restrict__ Q16,
    const _Float16* __restrict__ R16, const _Float16* __restrict__ WdT,
    const _Float16* __restrict__ W2T, const float* __restrict__ b2,
    const _Float16* __restrict__ cw1T, const float* __restrict__ cb1,
    const float* __restrict__ cw2,
    float* __restrict__ aggsum, float* __restrict__ outsum, int E)
{
    __shared__ __align__(16) _Float16 xt[4][32 * PST];  // 4 x 8.7 KB, wave-private
    __shared__ int   eaW[4][32], ebW[4][32], egW[4][32];
    __shared__ float fdW[LAST ? 4 : 1][32][3];
    __shared__ float gateW[LAST ? 4 : 1][32];

    int tid  = threadIdx.x;
    int wv   = tid >> 6, lane = tid & 63;
    int l31  = lane & 31, lh = lane >> 5;
    int s0   = blockIdx.x * 128 + wv * 32;

    _Float16* XT  = xt[wv];
    int* eaw = eaW[wv];
    int* ebw = ebW[wv];
    int* egw = egW[wv];

    // fragment-order weight bases (lane-contiguous)
    const _Float16* bwd = WdT  + (size_t)lane * 8;
    const _Float16* bw2 = W2T  + (size_t)lane * 8;

    // ---- wave-private meta stage
    if (lane < 32) {
        int s = s0 + lane;
        int a = 0, b = -1, g = 0;
        if (s < E) { a = eaS[s]; b = ebS[s]; g = egS[s]; }
        eaw[lane] = a; ebw[lane] = b; egw[lane] = g;
        if (LAST) {
            float f0 = 0.f, f1 = 0.f, f2 = 0.f;
            if (s < E) { f0 = fdS[s*3]; f1 = fdS[s*3+1]; f2 = fdS[s*3+2]; }
            fdW[wv][lane][0] = f0; fdW[wv][lane][1] = f1; fdW[wv][lane][2] = f2;
        }
    }

    // ---- in-wave dis feature build into XT as [32][DST] ----
    {
        int s = s0 + l31;
        float fd3[3] = {0.f, 0.f, 0.f};
        if (s < E) { fd3[0] = fdS[s*3]; fd3[1] = fdS[s*3+1]; fd3[2] = fdS[s*3+2]; }
        _Float16* dr = XT + l31 * DST + lh * 30;
        #pragma unroll
        for (int d = 0; d < 3; ++d) {
            float ang = 6.283185307179586f * fd3[d];
            float s1 = __sinf(ang), c1 = __cosf(ang);
            float tc = 2.f * c1;
            float m2 = lh ? 1.f : 0.f;       // w=0: cos=1, sin=0
            float m1 = lh ? c1  : s1;        // w=1
            half2v h01; h01[0] = (_Float16)m2; h01[1] = (_Float16)m1;
            *(half2v*)(dr + 10 * d) = h01;
            #pragma unroll
            for (int w = 2; w < 10; w += 2) {
                float a0 = tc * m1 - m2;
                float a1 = tc * a0 - m1;
                half2v hh; hh[0] = (_Float16)a0; hh[1] = (_Float16)a1;
                *(half2v*)(dr + 10 * d + w) = hh;
                m2 = a0; m1 = a1;
            }
        }
        // k = 60..63 zero pad (both halves write same value -> benign)
        half2v z; z[0] = (_Float16)0.f; z[1] = (_Float16)0.f;
        *(half2v*)(XT + l31 * DST + 60) = z;
        *(half2v*)(XT + l31 * DST + 62) = z;
    }
    WSYNC();                                         // dis + meta visible

    // ---- af[4] from LDS in A-fragment order (k = 16ks + 8lh + j)
    half8 af[4];
    {
        const _Float16* dp = XT + l31 * DST + lh * 8;
        af[0] = *(const half8*)(dp);      af[1] = *(const half8*)(dp + 16);
        af[2] = *(const half8*)(dp + 32); af[3] = *(const half8*)(dp + 48);
    }
    WSYNC();                                         // reads drained before overwrite

    // ---- gather + stage PQR tile (32 rows x 128 cols)
    #pragma unroll 4
    for (int k = 0; k < 8; ++k) {
        int c   = lane + 64 * k;
        int row = c >> 4, p8 = (c & 15) * 8;
        int a = eaw[row];
        int b = ebw[row]; if (b < 0) b = 0;
        int g = egw[row];
        half8 pv = *(const half8*)(P16 + (size_t)a * HD + p8);
        half8 qv = *(const half8*)(Q16 + (size_t)b * HD + p8);
        half8 rv = *(const half8*)(R16 + (size_t)g * HD + p8);
        *(half8*)(XT + row * PST + p8) = pv + qv + rv;
    }

    // ---- dis GEMM: K = 64, A from regs, 4 col-quads (cols 4*l31+i), frag-order B
    floatx16 acc[4] = {};
    #pragma unroll
    for (int ks = 0; ks < 4; ++ks) {
        #pragma unroll
        for (int i = 0; i < 4; ++i) {
            half8 b = *(const half8*)(bwd + (((ks << 2) | i) << 9));
            acc[i] = __builtin_amdgcn_mfma_f32_32x32x16_f16(af[ks], b, acc[i], 0, 0, 0);
        }
    }
    WSYNC();                                         // staging writes drained

    // ---- x1 = silu(accD + PQR), lane-owned half4 (cols 4*l31..+3)
    #pragma unroll
    for (int r = 0; r < 16; ++r) {
        int row = (r & 3) + 8 * (r >> 2) + 4 * lh;
        half4 pq = *(const half4*)(XT + row * PST + 4 * l31);
        half4 o;
        #pragma unroll
        for (int i = 0; i < 4; ++i)
            o[i] = (_Float16)silu_f(acc[i][r] + (float)pq[i]);
        *(half4*)(XT + row * PST + 4 * l31) = o;
    }
    WSYNC();                                         // x1 visible

    // ---- GEMM2: ef = silu(x1 @ W2 + b2), K = 128, frag-order B
    #pragma unroll
    for (int i = 0; i < 4; ++i) acc[i] = (floatx16){};
    for (int ks = 0; ks < 8; ++ks) {
        half8 a = *(const half8*)(XT + (size_t)l31 * PST + ks * 16 + lh * 8);
        #pragma unroll
        for (int i = 0; i < 4; ++i) {
            half8 b = *(const half8*)(bw2 + (((ks << 2) | i) << 9));
            acc[i] = __builtin_amdgcn_mfma_f32_32x32x16_f16(a, b, acc[i], 0, 0, 0);
        }
    }
    {
        float4 b2v = *(const float4*)(b2 + 4 * l31);
        #pragma unroll
        for (int r = 0; r < 16; ++r) {
            int row = (r & 3) + 8 * (r >> 2) + 4 * lh;
            half4 o;
            o[0] = (_Float16)silu_f(acc[0][r] + b2v.x);
            o[1] = (_Float16)silu_f(acc[1][r] + b2v.y);
            o[2] = (_Float16)silu_f(acc[2][r] + b2v.z);
            o[3] = (_Float16)silu_f(acc[3][r] + b2v.w);
            *(half4*)(XT + row * PST + 4 * l31) = o;
        }
    }
    WSYNC();                                         // ef visible

    if (!LAST) {
        // ---- run-reduced scatter (edges sorted by dest), lane owns col pair
        int c2 = lane * 2;
        float sx = 0.f, sy = 0.f;
        int cur = -1;
        for (int r = 0; r < 32; ++r) {
            int d = ebw[r];
            half2v v = *(const half2v*)(XT + r * PST + c2);
            float vx = (float)v[0], vy = (float)v[1];
            if (d != cur) {
                if (cur >= 0) {
                    atomicAdd(&aggsum[(size_t)cur * HD + c2],     sx);
                    atomicAdd(&aggsum[(size_t)cur * HD + c2 + 1], sy);
                }
                cur = d; sx = vx; sy = vy;
            } else { sx += vx; sy += vy; }
        }
        if (cur >= 0) {
            atomicAdd(&aggsum[(size_t)cur * HD + c2],     sx);
            atomicAdd(&aggsum[(size_t)cur * HD + c2 + 1], sy);
        }
    } else {
        // ---- GEMM3: g1 = silu(ef @ cw1 + cb1); gate = g1 @ cw2, frag-order B
        const _Float16* bw3 = cw1T + (size_t)lane * 8;
        #pragma unroll
        for (int i = 0; i < 4; ++i) acc[i] = (floatx16){};
        for (int ks = 0; ks < 8; ++ks) {
            half8 a = *(const half8*)(XT + (size_t)l31 * PST + ks * 16 + lh * 8);
            #pragma unroll
            for (int i = 0; i < 4; ++i) {
                half8 b = *(const half8*)(bw3 + (((ks << 2) | i) << 9));
                acc[i] = __builtin_amdgcn_mfma_f32_32x32x16_f16(a, b, acc[i], 0, 0, 0);
            }
        }
        float4 cbv = *(const float4*)(cb1 + 4 * l31);
        float4 wv4 = *(const float4*)(cw2 + 4 * l31);
        #pragma unroll
        for (int r = 0; r < 16; ++r) {
            float p = silu_f(acc[0][r] + cbv.x) * wv4.x
                    + silu_f(acc[1][r] + cbv.y) * wv4.y
                    + silu_f(acc[2][r] + cbv.z) * wv4.z
                    + silu_f(acc[3][r] + cbv.w) * wv4.w;
            p += __shfl_xor(p, 16);
            p += __shfl_xor(p, 8);
            p += __shfl_xor(p, 4);
            p += __shfl_xor(p, 2);
            p += __shfl_xor(p, 1);
            if (l31 == 0) {
                int row = (r & 3) + 8 * (r >> 2) + 4 * lh;
                gateW[wv][row] = p;                  // lanes 0 & 32 -> distinct rows
            }
        }
        WSYNC();                                     // gates visible
        if (lane < 32) {
            int r = lane, d = ebw[r];
            if (d >= 0 && (r == 0 || ebw[r - 1] != d)) {
                float sx = 0.f, sy = 0.f, sz = 0.f;
                for (int q = r; q < 32 && ebw[q] == d; ++q) {
                    float g = gateW[wv][q];
                    sx += fdW[wv][q][0] * g;
                    sy += fdW[wv][q][1] * g;
                    sz += fdW[wv][q][2] * g;
                }
                atomicAdd(&outsum[d * 3 + 0], sx);
                atomicAdd(&outsum[d * 3 + 1], sy);
                atomicAdd(&outsum[d * 3 + 2], sz);
            }
        }
    }
}

// ---- fused node update + next-layer P/Q: frag-order weights ----
__global__ __launch_bounds__(256) void k_node_pq(
    float* __restrict__ h, _Float16* __restrict__ h16,
    float* __restrict__ aggsum, const float* __restrict__ deginv,
    const _Float16* __restrict__ W1F, const float* __restrict__ b1,
    const _Float16* __restrict__ W2F, const float* __restrict__ b2,
    const _Float16* __restrict__ WaF, const _Float16* __restrict__ WbF,
    _Float16* __restrict__ P16, _Float16* __restrict__ Q16, int N)
{
    __shared__ __align__(16) _Float16 xs[32 * NST];   // 16.9 KB
    _Float16* x1s = xs;

    int tid = threadIdx.x;
    int n0  = blockIdx.x * 32;

    for (int c = tid; c < 32 * 16; c += 256) {
        int row = c >> 4, p = c & 15;
        int node = n0 + row;
        uint4 v = {0, 0, 0, 0};
        if (node < N) v = *(const uint4*)(h16 + (size_t)node * HD + p * 8);
        *(uint4*)(xs + row * NST + p * 8) = v;
    }
    for (int c = tid; c < 32 * 32; c += 256) {       // agg: float4 read+zero, half4 stage
        int row = c >> 5, q = c & 31;
        int node = n0 + row;
        float4 v = {0, 0, 0, 0};
        float di = 0.f;
        if (node < N) {
            size_t gi = (size_t)node * HD + q * 4;
            v = *(float4*)(aggsum + gi);
            *(float4*)(aggsum + gi) = make_float4(0.f, 0.f, 0.f, 0.f);
            di = deginv[node];
        }
        half4 o;
        o[0] = (_Float16)(v.x * di); o[1] = (_Float16)(v.y * di);
        o[2] = (_Float16)(v.z * di); o[3] = (_Float16)(v.w * di);
        *(half4*)(xs + row * NST + HD + q * 4) = o;
    }
    __syncthreads();

    int lane = tid & 63, wv = tid >> 6;
    int l31 = lane & 31, lh = lane >> 5;
    int nc  = wv * 32 + l31;                 // lane's single output col for GEMM1/2

    floatx16 acc0 = {};
    {
        const _Float16* ap = xs + (size_t)l31 * NST + lh * 8;
        const _Float16* bp = W1F + (size_t)wv * 512 + lane * 8;   // mode-2 blob
        for (int ks = 0; ks < 16; ++ks) {
            half8 a = *(const half8*)(ap + ks * 16);
            acc0 = __builtin_amdgcn_mfma_f32_32x32x16_f16(a, *(const half8*)(bp + ks * 2048), acc0, 0, 0, 0);
        }
    }
    __syncthreads();
    {
        float b10 = b1[nc];
        #pragma unroll
        for (int r = 0; r < 16; ++r) {
            int row = (r & 3) + 8 * (r >> 2) + 4 * lh;
            x1s[row * XST + nc] = (_Float16)silu_f(acc0[r] + b10);
        }
    }
    __syncthreads();

    acc0 = {};
    {
        const _Float16* ap = x1s + (size_t)l31 * XST + lh * 8;
        const _Float16* bp = W2F + (size_t)wv * 512 + lane * 8;   // mode-2 blob
        for (int ks = 0; ks < 8; ++ks) {
            half8 a = *(const half8*)(ap + ks * 16);
            acc0 = __builtin_amdgcn_mfma_f32_32x32x16_f16(a, *(const half8*)(bp + ks * 2048), acc0, 0, 0, 0);
        }
    }
    __syncthreads();   // all waves done reading x1s before restage

    {
        float b20 = b2[nc];
        #pragma unroll
        for (int r = 0; r < 16; ++r) {
            int row = (r & 3) + 8 * (r >> 2) + 4 * lh;
            int node = n0 + row;
            float v0 = silu_f(acc0[r] + b20);
            _Float16 hv;
            if (node < N) {
                size_t g0 = (size_t)node * HD + nc;
                v0 += h[g0];
                h[g0] = v0;
                hv = (_Float16)v0;
                h16[g0] = hv;
            } else hv = (_Float16)0.f;
            xs[row * PST + nc] = hv;
        }
    }
    __syncthreads();

    // next-layer P/Q: waves 0,1 -> P sub-pairs {0,1}/{2,3}; waves 2,3 -> Q (mode-0 blobs)
    {
        const _Float16* BT  = (wv >> 1) ? WbF : WaF;
        _Float16*       OUT = (wv >> 1) ? Q16 : P16;
        int sp = 2 * (wv & 1);                       // sub-pair base
        int c0 = 4 * l31 + sp;
        floatx16 a0 = {}, a1 = {};
        const _Float16* bp = BT + (size_t)sp * 512 + lane * 8;
        const _Float16* ap = xs + (size_t)l31 * PST + lh * 8;
        for (int ks = 0; ks < 8; ++ks) {
            half8 a = *(const half8*)(ap + ks * 16);
            a0 = __builtin_amdgcn_mfma_f32_32x32x16_f16(a, *(const half8*)(bp + ks * 2048), a0, 0, 0, 0);
            a1 = __builtin_amdgcn_mfma_f32_32x32x16_f16(a, *(const half8*)(bp + ks * 2048 + 512), a1, 0, 0, 0);
        }
        #pragma unroll
        for (int r = 0; r < 16; ++r) {
            int row = (r & 3) + 8 * (r >> 2) + 4 * lh;
            int node = n0 + row;
            if (node < N) {
                half2v o; o[0] = (_Float16)a0[r]; o[1] = (_Float16)a1[r];
                *(half2v*)(OUT + (size_t)node * HD + c0) = o;
            }
        }
    }
}

// ---------------- launcher ----------------
extern "C" void kernel_launch(void* const* d_in, const int* in_sizes, int n_in,
                              void* d_out, int out_size, void* d_ws, size_t ws_size,
                              hipStream_t stream)
{
    const int*   at    = (const int*)  d_in[0];
    const float* t     = (const float*)d_in[1];
    const float* fc    = (const float*)d_in[2];
    const int*   ei    = (const int*)  d_in[3];
    const float* lat   = (const float*)d_in[4];
    const int*   n2g   = (const int*)  d_in[5];
    const float* embed = (const float*)d_in[6];
    const float* lat_w = (const float*)d_in[7];
    const float* lat_b = (const float*)d_in[8];
    const float* ew1   = (const float*)d_in[9];
    const float* eb1   = (const float*)d_in[10];
    const float* ew2   = (const float*)d_in[11];
    const float* eb2   = (const float*)d_in[12];
    const float* nw1   = (const float*)d_in[13];
    const float* nb1   = (const float*)d_in[14];
    const float* nw2   = (const float*)d_in[15];
    const float* nb2   = (const float*)d_in[16];
    const float* cw1   = (const float*)d_in[17];
    const float* cb1   = (const float*)d_in[18];
    const float* cw2   = (const float*)d_in[19];

    int N = in_sizes[0];
    int E = in_sizes[3] / 2;
    int G = in_sizes[4] / 9;

    // ---- workspace carve ----
    char* p = (char*)d_ws;
    float* h      = (float*)p;  p += (size_t)N * HD * 4;
    float* aggsum = (float*)p;  p += (size_t)N * HD * 4;   // zeroed below
    float* outsum = (float*)p;  p += (size_t)N * 3 * 4;    // zeroed below
    int*   cnt    = (int*)p;    p += (size_t)N * 4;        // zeroed below
    int*   head   = (int*)p;    p += (size_t)N * 4;
    float* deginv = (float*)p;  p += (size_t)N * 4;
    float* latip  = (float*)p;  p += (size_t)G * 9 * 4;
    int*   perm   = (int*)p;    p += (size_t)E * 4;
    int*   eaS    = (int*)p;    p += (size_t)E * 4;
    int*   ebS    = (int*)p;    p += (size_t)E * 4;
    int*   egS    = (int*)p;    p += (size_t)E * 4;
    float* fdS    = (float*)p;  p += (size_t)E * 3 * 4;
    _Float16* h16   = (_Float16*)p; p += (size_t)N * HD * 2;
    _Float16* P16   = (_Float16*)p; p += (size_t)N * HD * 2;
    _Float16* Q16   = (_Float16*)p; p += (size_t)N * HD * 2;
    _Float16* w1aT  = (_Float16*)p; p += (size_t)4 * HD * HD * 2;
    _Float16* w1bT  = (_Float16*)p; p += (size_t)4 * HD * HD * 2;
    _Float16* wdT   = (_Float16*)p; p += (size_t)4 * HD * 64 * 2;
    _Float16* w2T   = (_Float16*)p; p += (size_t)4 * HD * HD * 2;
    _Float16* nw1T  = (_Float16*)p; p += (size_t)3 * HD * 256 * 2;
    _Float16* nw2T  = (_Float16*)p; p += (size_t)3 * HD * HD * 2;
    _Float16* cw1T  = (_Float16*)p; p += (size_t)HD * HD * 2;
    _Float16* latwT = (_Float16*)p; p += (size_t)HD * 400 * 2;
    _Float16* R16   = (_Float16*)p; p += (size_t)4 * G * HD * 2;

    // zero aggsum|outsum|cnt (contiguous)
    hipMemsetAsync(aggsum, 0, ((size_t)N * HD + (size_t)N * 3 + N) * 4, stream);

    // weight prep (all fragment-order: mode 0 = quad, 1 = pair, 2 = single-col)
    {
        int tot;
        tot = 4 * 8 * 2048;  k_wfragU<<<(tot+255)/256, 256, 0, stream>>>(ew1,  w1aT, EIN, 0,   128, 8,  4, 0);
        tot = 4 * 8 * 2048;  k_wfragU<<<(tot+255)/256, 256, 0, stream>>>(ew1,  w1bT, EIN, 128, 128, 8,  4, 0);
        tot = 4 * 4 * 2048;  k_wfragU<<<(tot+255)/256, 256, 0, stream>>>(ew1,  wdT,  EIN, 265, 60,  4,  4, 0);
        tot = 4 * 8 * 2048;  k_wfragU<<<(tot+255)/256, 256, 0, stream>>>(ew2,  w2T,  HD,  0,  128, 8,  4, 0);
        tot = 3 * 16 * 2048; k_wfragU<<<(tot+255)/256, 256, 0, stream>>>(nw1,  nw1T, 256, 0,  256, 16, 3, 2);
        tot = 3 * 8 * 2048;  k_wfragU<<<(tot+255)/256, 256, 0, stream>>>(nw2,  nw2T, HD,  0,  128, 8,  3, 2);
        tot = 1 * 8 * 2048;  k_wfragU<<<(tot+255)/256, 256, 0, stream>>>(cw1,  cw1T, HD,  0,  128, 8,  1, 0);
        tot = 25 * 2048;     k_wfragU<<<(tot+255)/256, 256, 0, stream>>>(lat_w, latwT, 384, 0, 384, 25, 1, 1);
    }

    k_latip  <<<(G * 9 + 255) / 256, 256, 0, stream>>>(lat, latip, G);
    k_hist   <<<(E + 255) / 256,     256, 0, stream>>>(ei + E, cnt, E);
    k_scan   <<<1, 1024, 0, stream>>>(cnt, head, N);
    k_deginv <<<(N + 255) / 256,     256, 0, stream>>>(cnt, deginv, N);
    k_scatter<<<(E + 255) / 256,     256, 0, stream>>>(ei + E, head, perm, E);
    k_esort  <<<(E + 255) / 256,     256, 0, stream>>>(ei, n2g, fc, perm, eaS, ebS, egS, fdS, E);
    k_rlat   <<<(4 * G * HD + 255) / 256, 256, 0, stream>>>(latip, ew1, eb1, R16, G);
    k_init_pq<<<(N + 63) / 64, 256, 0, stream>>>(at, t, embed, latwT, lat_b, h, h16,
                                                 w1aT, w1bT, P16, Q16, N);

    int eblocks = (E + 127) / 128;
    int nblocks = (N + 31) / 32;
    for (int l = 0; l < 3; ++l) {
        k_edge<false><<<eblocks, 256, 0, stream>>>(eaS, ebS, egS, fdS, P16, Q16,
            R16 + (size_t)l * G * HD, wdT + (size_t)l * HD * 64,
            w2T + (size_t)l * HD * HD, eb2 + l * HD,
            cw1T, cb1, cw2, aggsum, outsum, E);
        k_node_pq<<<nblocks, 256, 0, stream>>>(h, h16, aggsum, deginv,
            nw1T + (size_t)l * HD * 256, nb1 + l * HD,
            nw2T + (size_t)l * HD * HD,  nb2 + l * HD,
            w1aT + (size_t)(l + 1) * HD * HD, w1bT + (size_t)(l + 1) * HD * HD,
            P16, Q16, N);
    }
    k_edge<true><<<eblocks, 256, 0, stream>>>(eaS, ebS, egS, fdS, P16, Q16,
        R16 + (size_t)3 * G * HD, wdT + (size_t)3 * HD * 64,
        w2T + (size_t)3 * HD * HD, eb2 + 3 * HD,
        cw1T, cb1, cw2, aggsum, outsum, E);

    k_fin<<<(N * 3 + 255) / 256, 256, 0, stream>>>(outsum, deginv, (float*)d_out, N);
}

// Round 11
// 490.453 us; speedup vs baseline: 1.3320x; 1.0188x over previous
//
#include <hip/hip_runtime.h>
#include <hip/hip_bf16.h>
#include <hip/hip_fp16.h>
#include <math.h>

#define HD    128
#define EIN   325
#define PST   136      // edge tile row stride (f16), 16B-aligned
#define DST   72       // dis feature row stride (f16): 144B rows, 16B-aligned
#define NST   264      // node A-tile row stride (f16)
#define XST   136      // node x1 tile row stride
#define IST   408      // init A-tile row stride (400+8)

typedef _Float16 half8 __attribute__((ext_vector_type(8)));
typedef _Float16 half4 __attribute__((ext_vector_type(4)));
typedef _Float16 half2v __attribute__((ext_vector_type(2)));
typedef float    floatx16 __attribute__((ext_vector_type(16)));

// intra-wave LDS RAW fence (cross-lane write->read). Also a compiler memory fence.
#define WSYNC() __asm__ volatile("s_waitcnt lgkmcnt(0)" ::: "memory")

// fast silu: v_exp + v_rcp (approx) instead of IEEE div sequence
__device__ __forceinline__ float silu_f(float x) {
    return x * __builtin_amdgcn_rcpf(1.0f + __expf(-x));
}

// ---- fragment-order element writer (shared by all blobs) ----
// Blob: [m][blk][lane][8], blk = ks*4 + sub, lane = l31 + 32*lh, k = 16ks+8lh+j.
// mode 0: col = 4*l31 + sub               (quad consumers)
// mode 1: col = (sub>>1)*64+2*l31+(sub&1) (pair consumers: init latw)
// mode 2: col = sub*32 + l31              (single-col consumers: node W1/W2)
__device__ __forceinline__ void wfrag_elem(
    const float* __restrict__ src, _Float16* __restrict__ dst,
    int r_all, int Ktot, int krow0, int Kact, int nks, int mode)
{
    int per = nks * 2048;
    int m = r_all / per, r = r_all - m * per;
    int j    = r & 7;
    int lane = (r >> 3) & 63;
    int blk  = r >> 9;
    int ks = blk >> 2, sub = blk & 3;
    int l31 = lane & 31, lh = lane >> 5;
    int k   = 16 * ks + 8 * lh + j;
    int col;
    if (mode == 0)      col = 4 * l31 + sub;
    else if (mode == 1) col = (sub >> 1) * 64 + 2 * l31 + (sub & 1);
    else                col = sub * 32 + l31;
    float v = (k < Kact) ? src[(size_t)m * Ktot * HD + (size_t)(krow0 + k) * HD + col] : 0.f;
    dst[r_all] = (_Float16)v;
}

// ---- ONE kernel for all 8 weight blobs (block-range dispatch) ----
// ranges (blocks of 256): [0,256) w1aT | [256,512) w1bT | [512,640) wdT |
// [640,896) w2T | [896,1280) nw1T | [1280,1472) nw2T | [1472,1536) cw1T |
// [1536,1736) latwT
__global__ void k_wprep_all(
    const float* __restrict__ ew1, const float* __restrict__ ew2,
    const float* __restrict__ nw1, const float* __restrict__ nw2,
    const float* __restrict__ cw1, const float* __restrict__ lat_w,
    _Float16* __restrict__ w1aT, _Float16* __restrict__ w1bT,
    _Float16* __restrict__ wdT,  _Float16* __restrict__ w2T,
    _Float16* __restrict__ nw1T, _Float16* __restrict__ nw2T,
    _Float16* __restrict__ cw1T, _Float16* __restrict__ latwT)
{
    int b = blockIdx.x;
    int t = threadIdx.x;
    if (b < 256)       { wfrag_elem(ew1,  w1aT, (b       ) * 256 + t, EIN, 0,   128, 8,  0); }
    else if (b < 512)  { wfrag_elem(ew1,  w1bT, (b -  256) * 256 + t, EIN, 128, 128, 8,  0); }
    else if (b < 640)  { wfrag_elem(ew1,  wdT,  (b -  512) * 256 + t, EIN, 265, 60,  4,  0); }
    else if (b < 896)  { wfrag_elem(ew2,  w2T,  (b -  640) * 256 + t, HD,  0,   128, 8,  0); }
    else if (b < 1280) { wfrag_elem(nw1,  nw1T, (b -  896) * 256 + t, 256, 0,   256, 16, 2); }
    else if (b < 1472) { wfrag_elem(nw2,  nw2T, (b - 1280) * 256 + t, HD,  0,   128, 8,  2); }
    else if (b < 1536) { wfrag_elem(cw1,  cw1T, (b - 1472) * 256 + t, HD,  0,   128, 8,  0); }
    else               { wfrag_elem(lat_w, latwT,(b - 1536) * 256 + t, 384, 0,  384, 25, 1); }
}

// ---- tiny kernels ----
__global__ void k_hist(const int* __restrict__ ei1, int* __restrict__ cnt, int E) {
    int idx = blockIdx.x * 256 + threadIdx.x;
    if (idx < E) atomicAdd(&cnt[ei1[idx]], 1);
}

// scan + deginv fused
__global__ __launch_bounds__(1024) void k_scan(const int* __restrict__ cnt,
                                               int* __restrict__ head,
                                               float* __restrict__ deginv, int N) {
    __shared__ int part[1024];
    int tid = threadIdx.x;
    int chunk = (N + 1023) >> 10;
    int start = tid * chunk, stop = min(start + chunk, N);
    int s = 0;
    for (int i = start; i < stop; ++i) s += cnt[i];
    part[tid] = s;
    __syncthreads();
    for (int off = 1; off < 1024; off <<= 1) {
        int v = (tid >= off) ? part[tid - off] : 0;
        __syncthreads();
        part[tid] += v;
        __syncthreads();
    }
    int run = (tid > 0) ? part[tid - 1] : 0;
    for (int i = start; i < stop; ++i) {
        head[i] = run;
        int c = cnt[i];
        run += c;
        deginv[i] = 1.0f / fmaxf((float)c, 1.0f);
    }
}

__global__ void k_scatter(const int* __restrict__ ei1, int* __restrict__ head,
                          int* __restrict__ perm, int E) {
    int e = blockIdx.x * 256 + threadIdx.x;
    if (e < E) {
        int d = ei1[e];
        int pos = atomicAdd(&head[d], 1);
        perm[pos] = e;
    }
}

// ---- sorted edge meta (dis features computed in-kernel in k_edge) ----
__global__ void k_esort(const int* __restrict__ ei, const int* __restrict__ n2g,
                        const float* __restrict__ fc, const int* __restrict__ perm,
                        int* __restrict__ eaS, int* __restrict__ ebS, int* __restrict__ egS,
                        float* __restrict__ fdS, int E) {
    int s = blockIdx.x * 256 + threadIdx.x;
    if (s >= E) return;
    int e = perm[s];
    int a = ei[e], b = ei[E + e];
    eaS[s] = a; ebS[s] = b; egS[s] = n2g[a];
    #pragma unroll
    for (int d = 0; d < 3; ++d) {
        float sh = fc[b * 3 + d] - fc[a * 3 + d];
        fdS[s * 3 + d] = sh - floorf(sh + 0.5f + 1e-4f);
    }
}

// ---- per-graph table with inline lat_ip: R[l][g][c] = latip[g] @ W1lat[l] + eb1[l] ----
__global__ void k_rlat(const float* __restrict__ lat, const float* __restrict__ ew1,
                       const float* __restrict__ eb1, _Float16* __restrict__ R16, int G) {
    int idx = blockIdx.x * 256 + threadIdx.x;
    if (idx >= 4 * G * HD) return;
    int l = idx / (G * HD), r = idx - l * (G * HD), g = r >> 7, c = r & 127;
    const float* L = lat + g * 9;
    const float* W = ew1 + (size_t)l * EIN * HD + 256 * HD;  // k-rows 256..264
    float s = eb1[l * HD + c];
    #pragma unroll
    for (int i = 0; i < 3; ++i)
        #pragma unroll
        for (int k = 0; k < 3; ++k) {
            float lp = L[i*3+0]*L[k*3+0] + L[i*3+1]*L[k*3+1] + L[i*3+2]*L[k*3+2];
            s = fmaf(lp, W[(i * 3 + k) * HD + c], s);
        }
    R16[idx] = (_Float16)s;
}

__global__ void k_fin(const float* __restrict__ outsum, const float* __restrict__ deginv,
                      float* __restrict__ out, int N) {
    int idx = blockIdx.x * 256 + threadIdx.x;
    if (idx < N * 3) out[idx] = outsum[idx] * deginv[idx / 3];
}

// ---- node init fused with first P/Q (frag-order weights) ----
__global__ __launch_bounds__(256) void k_init_pq(
    const int* __restrict__ at, const float* __restrict__ t,
    const float* __restrict__ embed, const _Float16* __restrict__ latwF,
    const float* __restrict__ lat_b, float* __restrict__ h,
    _Float16* __restrict__ h16,
    const _Float16* __restrict__ WaF, const _Float16* __restrict__ WbF,
    _Float16* __restrict__ P16, _Float16* __restrict__ Q16, int N)
{
    __shared__ __align__(16) _Float16 xs[64 * IST];   // 51 KB
    __shared__ int   atL[64];
    __shared__ float tL[64];
    __shared__ float frL[128];
    int tid = threadIdx.x;
    int n0  = blockIdx.x * 64;

    if (tid < 64) {
        int node = n0 + tid;
        atL[tid] = (node < N) ? at[node] - 1 : 0;
        tL[tid]  = (node < N) ? t[node] : 0.f;
    }
    if (tid < 128) frL[tid] = __expf(-(float)tid * 0.07252236514f);
    __syncthreads();

    for (int c = tid; c < 64 * 32; c += 256) {       // embed cols 0..127
        int row = c >> 5, p = c & 31;
        float4 v = {0, 0, 0, 0};
        if (n0 + row < N) v = *(const float4*)(embed + (size_t)atL[row] * HD + p * 4);
        _Float16* d = xs + row * IST + p * 4;
        d[0] = (_Float16)v.x; d[1] = (_Float16)v.y; d[2] = (_Float16)v.z; d[3] = (_Float16)v.w;
    }
    for (int c = tid; c < 64 * 272; c += 256) {      // sin/cos cols 128..383 + pad
        int row = c / 272, j = c - row * 272;
        float v = 0.f;
        if (j < 256 && n0 + row < N) {
            int k = j & 127;
            float a = tL[row] * frL[k];
            v = (j < 128) ? __sinf(a) : __cosf(a);
        }
        xs[row * IST + 128 + j] = (_Float16)v;
    }
    __syncthreads();

    int lane = tid & 63, wv = tid >> 6;
    int l31 = lane & 31, lh = lane >> 5;
    int rm = (wv >> 1) * 32, cb = (wv & 1) * 64;
    int n0c = cb + 2 * l31, n1c = n0c + 1;           // interleaved col ownership

    floatx16 acc0 = {}, acc1 = {};
    {
        const _Float16* ap = xs + (size_t)(rm + l31) * IST + lh * 8;
        const _Float16* bp = latwF + (size_t)(wv & 1) * 1024 + lane * 8;  // mode-1 blob
        for (int ks = 0; ks < 25; ++ks) {
            half8 a  = *(const half8*)(ap + ks * 16);
            acc0 = __builtin_amdgcn_mfma_f32_32x32x16_f16(a, *(const half8*)(bp + ks * 2048), acc0, 0, 0, 0);
            acc1 = __builtin_amdgcn_mfma_f32_32x32x16_f16(a, *(const half8*)(bp + ks * 2048 + 512), acc1, 0, 0, 0);
        }
    }
    __syncthreads();   // all waves done reading xs A-tile

    {
        float2 bb = *(const float2*)(lat_b + n0c);
        #pragma unroll
        for (int r = 0; r < 16; ++r) {
            int row = rm + (r & 3) + 8 * (r >> 2) + 4 * lh;
            int node = n0 + row;
            float v0 = acc0[r] + bb.x, v1 = acc1[r] + bb.y;
            half2v h2; h2[0] = (_Float16)v0; h2[1] = (_Float16)v1;
            if (node < N) {
                *(float2*)(h + (size_t)node * HD + n0c) = make_float2(v0, v1);
                *(half2v*)(h16 + (size_t)node * HD + n0c) = h2;
            }
            *(half2v*)(xs + row * PST + n0c) = h2;   // stage for PQ GEMMs
        }
    }
    __syncthreads();

    // P/Q GEMMs: wave wv&1 selects matrix; cols 4*l31+i (mode-0 frag blobs)
    {
        const _Float16* BT  = (wv & 1) ? WbF : WaF;
        _Float16*       OUT = (wv & 1) ? Q16 : P16;
        floatx16 acc[4] = {};
        const _Float16* ap = xs + (size_t)(rm + l31) * PST + lh * 8;
        const _Float16* bp = BT + (size_t)lane * 8;
        for (int ks = 0; ks < 8; ++ks) {
            half8 a = *(const half8*)(ap + ks * 16);
            #pragma unroll
            for (int i = 0; i < 4; ++i) {
                half8 b = *(const half8*)(bp + ks * 2048 + i * 512);
                acc[i] = __builtin_amdgcn_mfma_f32_32x32x16_f16(a, b, acc[i], 0, 0, 0);
            }
        }
        #pragma unroll
        for (int r = 0; r < 16; ++r) {
            int row = rm + (r & 3) + 8 * (r >> 2) + 4 * lh;
            int node = n0 + row;
            if (node < N) {
                half4 o;
                #pragma unroll
                for (int i = 0; i < 4; ++i) o[i] = (_Float16)acc[i][r];
                *(half4*)(OUT + (size_t)node * HD + 4 * l31) = o;
            }
        }
    }
}

// ---- fused edge kernel: WAVE-OWNED 32-edge tiles, ZERO __syncthreads ----
template <bool LAST>
__global__ __launch_bounds__(256, 4) void k_edge(
    const int* __restrict__ eaS, const int* __restrict__ ebS,
    const int* __restrict__ egS, const float* __restrict__ fdS,
    const _Float16* __restrict__ P16, const _Float16* __restrict__ Q16,
    const _Float16* __restrict__ R16, const _Float16* __restrict__ WdT,
    const _Float16* __restrict__ W2T, const float* __restrict__ b2,
    const _Float16* __restrict__ cw1T, const float* __restrict__ cb1,
    const float* __restrict__ cw2,
    float* __restrict__ aggsum, float* __restrict__ outsum, int E)
{
    __shared__ __align__(16) _Float16 xt[4][32 * PST];  // 4 x 8.7 KB, wave-private
    __shared__ int   eaW[4][32], ebW[4][32], egW[4][32];
    __shared__ float fdW[LAST ? 4 : 1][32][3];
    __shared__ float gateW[LAST ? 4 : 1][32];

    int tid  = threadIdx.x;
    int wv   = tid >> 6, lane = tid & 63;
    int l31  = lane & 31, lh = lane >> 5;
    int s0   = blockIdx.x * 128 + wv * 32;

    _Float16* XT  = xt[wv];
    int* eaw = eaW[wv];
    int* ebw = ebW[wv];
    int* egw = egW[wv];

    // fragment-order weight bases (lane-contiguous)
    const _Float16* bwd = WdT  + (size_t)lane * 8;
    const _Float16* bw2 = W2T  + (size_t)lane * 8;

    // ---- wave-private meta stage
    if (lane < 32) {
        int s = s0 + lane;
        int a = 0, b = -1, g = 0;
        if (s < E) { a = eaS[s]; b = ebS[s]; g = egS[s]; }
        eaw[lane] = a; ebw[lane] = b; egw[lane] = g;
        if (LAST) {
            float f0 = 0.f, f1 = 0.f, f2 = 0.f;
            if (s < E) { f0 = fdS[s*3]; f1 = fdS[s*3+1]; f2 = fdS[s*3+2]; }
            fdW[wv][lane][0] = f0; fdW[wv][lane][1] = f1; fdW[wv][lane][2] = f2;
        }
    }

    // ---- in-wave dis feature build into XT as [32][DST] ----
    {
        int s = s0 + l31;
        float fd3[3] = {0.f, 0.f, 0.f};
        if (s < E) { fd3[0] = fdS[s*3]; fd3[1] = fdS[s*3+1]; fd3[2] = fdS[s*3+2]; }
        _Float16* dr = XT + l31 * DST + lh * 30;
        #pragma unroll
        for (int d = 0; d < 3; ++d) {
            float ang = 6.283185307179586f * fd3[d];
            float s1 = __sinf(ang), c1 = __cosf(ang);
            float tc = 2.f * c1;
            float m2 = lh ? 1.f : 0.f;       // w=0: cos=1, sin=0
            float m1 = lh ? c1  : s1;        // w=1
            half2v h01; h01[0] = (_Float16)m2; h01[1] = (_Float16)m1;
            *(half2v*)(dr + 10 * d) = h01;
            #pragma unroll
            for (int w = 2; w < 10; w += 2) {
                float a0 = tc * m1 - m2;
                float a1 = tc * a0 - m1;
                half2v hh; hh[0] = (_Float16)a0; hh[1] = (_Float16)a1;
                *(half2v*)(dr + 10 * d + w) = hh;
                m2 = a0; m1 = a1;
            }
        }
        // k = 60..63 zero pad (both halves write same value -> benign)
        half2v z; z[0] = (_Float16)0.f; z[1] = (_Float16)0.f;
        *(half2v*)(XT + l31 * DST + 60) = z;
        *(half2v*)(XT + l31 * DST + 62) = z;
    }
    WSYNC();                                         // dis + meta visible

    // ---- af[4] from LDS in A-fragment order (k = 16ks + 8lh + j)
    half8 af[4];
    {
        const _Float16* dp = XT + l31 * DST + lh * 8;
        af[0] = *(const half8*)(dp);      af[1] = *(const half8*)(dp + 16);
        af[2] = *(const half8*)(dp + 32); af[3] = *(const half8*)(dp + 48);
    }
    WSYNC();                                         // reads drained before overwrite

    // ---- gather + stage PQR tile (32 rows x 128 cols)
    #pragma unroll 4
    for (int k = 0; k < 8; ++k) {
        int c   = lane + 64 * k;
        int row = c >> 4, p8 = (c & 15) * 8;
        int a = eaw[row];
        int b = ebw[row]; if (b < 0) b = 0;
        int g = egw[row];
        half8 pv = *(const half8*)(P16 + (size_t)a * HD + p8);
        half8 qv = *(const half8*)(Q16 + (size_t)b * HD + p8);
        half8 rv = *(const half8*)(R16 + (size_t)g * HD + p8);
        *(half8*)(XT + row * PST + p8) = pv + qv + rv;
    }

    // ---- dis GEMM: K = 64, A from regs, 4 col-quads (cols 4*l31+i), frag-order B
    floatx16 acc[4] = {};
    #pragma unroll
    for (int ks = 0; ks < 4; ++ks) {
        #pragma unroll
        for (int i = 0; i < 4; ++i) {
            half8 b = *(const half8*)(bwd + (((ks << 2) | i) << 9));
            acc[i] = __builtin_amdgcn_mfma_f32_32x32x16_f16(af[ks], b, acc[i], 0, 0, 0);
        }
    }
    WSYNC();                                         // staging writes drained

    // ---- x1 = silu(accD + PQR), lane-owned half4 (cols 4*l31..+3)
    #pragma unroll
    for (int r = 0; r < 16; ++r) {
        int row = (r & 3) + 8 * (r >> 2) + 4 * lh;
        half4 pq = *(const half4*)(XT + row * PST + 4 * l31);
        half4 o;
        #pragma unroll
        for (int i = 0; i < 4; ++i)
            o[i] = (_Float16)silu_f(acc[i][r] + (float)pq[i]);
        *(half4*)(XT + row * PST + 4 * l31) = o;
    }
    WSYNC();                                         // x1 visible

    // ---- GEMM2: ef = silu(x1 @ W2 + b2), K = 128, frag-order B
    #pragma unroll
    for (int i = 0; i < 4; ++i) acc[i] = (floatx16){};
    for (int ks = 0; ks < 8; ++ks) {
        half8 a = *(const half8*)(XT + (size_t)l31 * PST + ks * 16 + lh * 8);
        #pragma unroll
        for (int i = 0; i < 4; ++i) {
            half8 b = *(const half8*)(bw2 + (((ks << 2) | i) << 9));
            acc[i] = __builtin_amdgcn_mfma_f32_32x32x16_f16(a, b, acc[i], 0, 0, 0);
        }
    }
    {
        float4 b2v = *(const float4*)(b2 + 4 * l31);
        #pragma unroll
        for (int r = 0; r < 16; ++r) {
            int row = (r & 3) + 8 * (r >> 2) + 4 * lh;
            half4 o;
            o[0] = (_Float16)silu_f(acc[0][r] + b2v.x);
            o[1] = (_Float16)silu_f(acc[1][r] + b2v.y);
            o[2] = (_Float16)silu_f(acc[2][r] + b2v.z);
            o[3] = (_Float16)silu_f(acc[3][r] + b2v.w);
            *(half4*)(XT + row * PST + 4 * l31) = o;
        }
    }
    WSYNC();                                         // ef visible

    if (!LAST) {
        // ---- run-reduced scatter (edges sorted by dest), lane owns col pair
        int c2 = lane * 2;
        float sx = 0.f, sy = 0.f;
        int cur = -1;
        for (int r = 0; r < 32; ++r) {
            int d = ebw[r];
            half2v v = *(const half2v*)(XT + r * PST + c2);
            float vx = (float)v[0], vy = (float)v[1];
            if (d != cur) {
                if (cur >= 0) {
                    atomicAdd(&aggsum[(size_t)cur * HD + c2],     sx);
                    atomicAdd(&aggsum[(size_t)cur * HD + c2 + 1], sy);
                }
                cur = d; sx = vx; sy = vy;
            } else { sx += vx; sy += vy; }
        }
        if (cur >= 0) {
            atomicAdd(&aggsum[(size_t)cur * HD + c2],     sx);
            atomicAdd(&aggsum[(size_t)cur * HD + c2 + 1], sy);
        }
    } else {
        // ---- GEMM3: g1 = silu(ef @ cw1 + cb1); gate = g1 @ cw2, frag-order B
        const _Float16* bw3 = cw1T + (size_t)lane * 8;
        #pragma unroll
        for (int i = 0; i < 4; ++i) acc[i] = (floatx16){};
        for (int ks = 0; ks < 8; ++ks) {
            half8 a = *(const half8*)(XT + (size_t)l31 * PST + ks * 16 + lh * 8);
            #pragma unroll
            for (int i = 0; i < 4; ++i) {
                half8 b = *(const half8*)(bw3 + (((ks << 2) | i) << 9));
                acc[i] = __builtin_amdgcn_mfma_f32_32x32x16_f16(a, b, acc[i], 0, 0, 0);
            }
        }
        float4 cbv = *(const float4*)(cb1 + 4 * l31);
        float4 wv4 = *(const float4*)(cw2 + 4 * l31);
        #pragma unroll
        for (int r = 0; r < 16; ++r) {
            float p = silu_f(acc[0][r] + cbv.x) * wv4.x
                    + silu_f(acc[1][r] + cbv.y) * wv4.y
                    + silu_f(acc[2][r] + cbv.z) * wv4.z
                    + silu_f(acc[3][r] + cbv.w) * wv4.w;
            p += __shfl_xor(p, 16);
            p += __shfl_xor(p, 8);
            p += __shfl_xor(p, 4);
            p += __shfl_xor(p, 2);
            p += __shfl_xor(p, 1);
            if (l31 == 0) {
                int row = (r & 3) + 8 * (r >> 2) + 4 * lh;
                gateW[wv][row] = p;                  // lanes 0 & 32 -> distinct rows
            }
        }
        WSYNC();                                     // gates visible
        if (lane < 32) {
            int r = lane, d = ebw[r];
            if (d >= 0 && (r == 0 || ebw[r - 1] != d)) {
                float sx = 0.f, sy = 0.f, sz = 0.f;
                for (int q = r; q < 32 && ebw[q] == d; ++q) {
                    float g = gateW[wv][q];
                    sx += fdW[wv][q][0] * g;
                    sy += fdW[wv][q][1] * g;
                    sz += fdW[wv][q][2] * g;
                }
                atomicAdd(&outsum[d * 3 + 0], sx);
                atomicAdd(&outsum[d * 3 + 1], sy);
                atomicAdd(&outsum[d * 3 + 2], sz);
            }
        }
    }
}

// ---- fused node update + next-layer P/Q: frag-order weights ----
__global__ __launch_bounds__(256) void k_node_pq(
    float* __restrict__ h, _Float16* __restrict__ h16,
    float* __restrict__ aggsum, const float* __restrict__ deginv,
    const _Float16* __restrict__ W1F, const float* __restrict__ b1,
    const _Float16* __restrict__ W2F, const float* __restrict__ b2,
    const _Float16* __restrict__ WaF, const _Float16* __restrict__ WbF,
    _Float16* __restrict__ P16, _Float16* __restrict__ Q16, int N)
{
    __shared__ __align__(16) _Float16 xs[32 * NST];   // 16.9 KB
    _Float16* x1s = xs;

    int tid = threadIdx.x;
    int n0  = blockIdx.x * 32;

    for (int c = tid; c < 32 * 16; c += 256) {
        int row = c >> 4, p = c & 15;
        int node = n0 + row;
        uint4 v = {0, 0, 0, 0};
        if (node < N) v = *(const uint4*)(h16 + (size_t)node * HD + p * 8);
        *(uint4*)(xs + row * NST + p * 8) = v;
    }
    for (int c = tid; c < 32 * 32; c += 256) {       // agg: float4 read+zero, half4 stage
        int row = c >> 5, q = c & 31;
        int node = n0 + row;
        float4 v = {0, 0, 0, 0};
        float di = 0.f;
        if (node < N) {
            size_t gi = (size_t)node * HD + q * 4;
            v = *(float4*)(aggsum + gi);
            *(float4*)(aggsum + gi) = make_float4(0.f, 0.f, 0.f, 0.f);
            di = deginv[node];
        }
        half4 o;
        o[0] = (_Float16)(v.x * di); o[1] = (_Float16)(v.y * di);
        o[2] = (_Float16)(v.z * di); o[3] = (_Float16)(v.w * di);
        *(half4*)(xs + row * NST + HD + q * 4) = o;
    }
    __syncthreads();

    int lane = tid & 63, wv = tid >> 6;
    int l31 = lane & 31, lh = lane >> 5;
    int nc  = wv * 32 + l31;                 // lane's single output col for GEMM1/2

    floatx16 acc0 = {};
    {
        const _Float16* ap = xs + (size_t)l31 * NST + lh * 8;
        const _Float16* bp = W1F + (size_t)wv * 512 + lane * 8;   // mode-2 blob
        for (int ks = 0; ks < 16; ++ks) {
            half8 a = *(const half8*)(ap + ks * 16);
            acc0 = __builtin_amdgcn_mfma_f32_32x32x16_f16(a, *(const half8*)(bp + ks * 2048), acc0, 0, 0, 0);
        }
    }
    __syncthreads();
    {
        float b10 = b1[nc];
        #pragma unroll
        for (int r = 0; r < 16; ++r) {
            int row = (r & 3) + 8 * (r >> 2) + 4 * lh;
            x1s[row * XST + nc] = (_Float16)silu_f(acc0[r] + b10);
        }
    }
    __syncthreads();

    acc0 = {};
    {
        const _Float16* ap = x1s + (size_t)l31 * XST + lh * 8;
        const _Float16* bp = W2F + (size_t)wv * 512 + lane * 8;   // mode-2 blob
        for (int ks = 0; ks < 8; ++ks) {
            half8 a = *(const half8*)(ap + ks * 16);
            acc0 = __builtin_amdgcn_mfma_f32_32x32x16_f16(a, *(const half8*)(bp + ks * 2048), acc0, 0, 0, 0);
        }
    }
    __syncthreads();   // all waves done reading x1s before restage

    {
        float b20 = b2[nc];
        #pragma unroll
        for (int r = 0; r < 16; ++r) {
            int row = (r & 3) + 8 * (r >> 2) + 4 * lh;
            int node = n0 + row;
            float v0 = silu_f(acc0[r] + b20);
            _Float16 hv;
            if (node < N) {
                size_t g0 = (size_t)node * HD + nc;
                v0 += h[g0];
                h[g0] = v0;
                hv = (_Float16)v0;
                h16[g0] = hv;
            } else hv = (_Float16)0.f;
            xs[row * PST + nc] = hv;
        }
    }
    __syncthreads();

    // next-layer P/Q: waves 0,1 -> P sub-pairs {0,1}/{2,3}; waves 2,3 -> Q (mode-0 blobs)
    {
        const _Float16* BT  = (wv >> 1) ? WbF : WaF;
        _Float16*       OUT = (wv >> 1) ? Q16 : P16;
        int sp = 2 * (wv & 1);                       // sub-pair base
        int c0 = 4 * l31 + sp;
        floatx16 a0 = {}, a1 = {};
        const _Float16* bp = BT + (size_t)sp * 512 + lane * 8;
        const _Float16* ap = xs + (size_t)l31 * PST + lh * 8;
        for (int ks = 0; ks < 8; ++ks) {
            half8 a = *(const half8*)(ap + ks * 16);
            a0 = __builtin_amdgcn_mfma_f32_32x32x16_f16(a, *(const half8*)(bp + ks * 2048), a0, 0, 0, 0);
            a1 = __builtin_amdgcn_mfma_f32_32x32x16_f16(a, *(const half8*)(bp + ks * 2048 + 512), a1, 0, 0, 0);
        }
        #pragma unroll
        for (int r = 0; r < 16; ++r) {
            int row = (r & 3) + 8 * (r >> 2) + 4 * lh;
            int node = n0 + row;
            if (node < N) {
                half2v o; o[0] = (_Float16)a0[r]; o[1] = (_Float16)a1[r];
                *(half2v*)(OUT + (size_t)node * HD + c0) = o;
            }
        }
    }
}

// ---------------- launcher ----------------
extern "C" void kernel_launch(void* const* d_in, const int* in_sizes, int n_in,
                              void* d_out, int out_size, void* d_ws, size_t ws_size,
                              hipStream_t stream)
{
    const int*   at    = (const int*)  d_in[0];
    const float* t     = (const float*)d_in[1];
    const float* fc    = (const float*)d_in[2];
    const int*   ei    = (const int*)  d_in[3];
    const float* lat   = (const float*)d_in[4];
    const int*   n2g   = (const int*)  d_in[5];
    const float* embed = (const float*)d_in[6];
    const float* lat_w = (const float*)d_in[7];
    const float* lat_b = (const float*)d_in[8];
    const float* ew1   = (const float*)d_in[9];
    const float* eb1   = (const float*)d_in[10];
    const float* ew2   = (const float*)d_in[11];
    const float* eb2   = (const float*)d_in[12];
    const float* nw1   = (const float*)d_in[13];
    const float* nb1   = (const float*)d_in[14];
    const float* nw2   = (const float*)d_in[15];
    const float* nb2   = (const float*)d_in[16];
    const float* cw1   = (const float*)d_in[17];
    const float* cb1   = (const float*)d_in[18];
    const float* cw2   = (const float*)d_in[19];

    int N = in_sizes[0];
    int E = in_sizes[3] / 2;
    int G = in_sizes[4] / 9;

    // ---- workspace carve ----
    char* p = (char*)d_ws;
    float* h      = (float*)p;  p += (size_t)N * HD * 4;
    float* aggsum = (float*)p;  p += (size_t)N * HD * 4;   // zeroed below
    float* outsum = (float*)p;  p += (size_t)N * 3 * 4;    // zeroed below
    int*   cnt    = (int*)p;    p += (size_t)N * 4;        // zeroed below
    int*   head   = (int*)p;    p += (size_t)N * 4;
    float* deginv = (float*)p;  p += (size_t)N * 4;
    int*   perm   = (int*)p;    p += (size_t)E * 4;
    int*   eaS    = (int*)p;    p += (size_t)E * 4;
    int*   ebS    = (int*)p;    p += (size_t)E * 4;
    int*   egS    = (int*)p;    p += (size_t)E * 4;
    float* fdS    = (float*)p;  p += (size_t)E * 3 * 4;
    _Float16* h16   = (_Float16*)p; p += (size_t)N * HD * 2;
    _Float16* P16   = (_Float16*)p; p += (size_t)N * HD * 2;
    _Float16* Q16   = (_Float16*)p; p += (size_t)N * HD * 2;
    _Float16* w1aT  = (_Float16*)p; p += (size_t)4 * HD * HD * 2;
    _Float16* w1bT  = (_Float16*)p; p += (size_t)4 * HD * HD * 2;
    _Float16* wdT   = (_Float16*)p; p += (size_t)4 * HD * 64 * 2;
    _Float16* w2T   = (_Float16*)p; p += (size_t)4 * HD * HD * 2;
    _Float16* nw1T  = (_Float16*)p; p += (size_t)3 * HD * 256 * 2;
    _Float16* nw2T  = (_Float16*)p; p += (size_t)3 * HD * HD * 2;
    _Float16* cw1T  = (_Float16*)p; p += (size_t)HD * HD * 2;
    _Float16* latwT = (_Float16*)p; p += (size_t)HD * 400 * 2;
    _Float16* R16   = (_Float16*)p; p += (size_t)4 * G * HD * 2;

    // zero aggsum|outsum|cnt (contiguous)
    hipMemsetAsync(aggsum, 0, ((size_t)N * HD + (size_t)N * 3 + N) * 4, stream);

    // ---- all weight blobs in ONE launch (fragment-order) ----
    k_wprep_all<<<1736, 256, 0, stream>>>(ew1, ew2, nw1, nw2, cw1, lat_w,
                                          w1aT, w1bT, wdT, w2T, nw1T, nw2T, cw1T, latwT);

    k_hist   <<<(E + 255) / 256, 256, 0, stream>>>(ei + E, cnt, E);
    k_scan   <<<1, 1024, 0, stream>>>(cnt, head, deginv, N);
    k_scatter<<<(E + 255) / 256, 256, 0, stream>>>(ei + E, head, perm, E);
    k_esort  <<<(E + 255) / 256, 256, 0, stream>>>(ei, n2g, fc, perm, eaS, ebS, egS, fdS, E);
    k_rlat   <<<(4 * G * HD + 255) / 256, 256, 0, stream>>>(lat, ew1, eb1, R16, G);
    k_init_pq<<<(N + 63) / 64, 256, 0, stream>>>(at, t, embed, latwT, lat_b, h, h16,
                                                 w1aT, w1bT, P16, Q16, N);

    int eblocks = (E + 127) / 128;
    int nblocks = (N + 31) / 32;
    for (int l = 0; l < 3; ++l) {
        k_edge<false><<<eblocks, 256, 0, stream>>>(eaS, ebS, egS, fdS, P16, Q16,
            R16 + (size_t)l * G * HD, wdT + (size_t)l * HD * 64,
            w2T + (size_t)l * HD * HD, eb2 + l * HD,
            cw1T, cb1, cw2, aggsum, outsum, E);
        k_node_pq<<<nblocks, 256, 0, stream>>>(h, h16, aggsum, deginv,
            nw1T + (size_t)l * HD * 256, nb1 + l * HD,
            nw2T + (size_t)l * HD * HD,  nb2 + l * HD,
            w1aT + (size_t)(l + 1) * HD * HD, w1bT + (size_t)(l + 1) * HD * HD,
            P16, Q16, N);
    }
    k_edge<true><<<eblocks, 256, 0, stream>>>(eaS, ebS, egS, fdS, P16, Q16,
        R16 + (size_t)3 * G * HD, wdT + (size_t)3 * HD * 64,
        w2T + (size_t)3 * HD * HD, eb2 + 3 * HD,
        cw1T, cb1, cw2, aggsum, outsum, E);

    k_fin<<<(N * 3 + 255) / 256, 256, 0, stream>>>(outsum, deginv, (float*)d_out, N);
}